// Round 4
// baseline (25281.148 us; speedup 1.0000x reference)
//
#include <hip/hip_runtime.h>
#include <math.h>

// Problem dims
#define T_ 128
#define B_ 512
#define N_ 256
#define M_ 512
#define G_ 2048   // 4*M
#define NBLK 256  // persistent grid size (capacity 2/CU x 256 CU = 512 >= 256)

// ---------------------------------------------------------------------------
// Device-scope ticket barrier. Counter starts at 0 (memset by host each call).
// Release: __threadfence + agent-scope fetch_add (L2 writeback).
// Acquire: agent-scope spin load (cache invalidate). Same mechanism cg uses.
// ---------------------------------------------------------------------------
__device__ __forceinline__ void grid_bar(int* bar) {
    __syncthreads();
    if (threadIdx.x == 0) {
        __threadfence();
        int ticket = __hip_atomic_fetch_add(bar, 1, __ATOMIC_ACQ_REL,
                                            __HIP_MEMORY_SCOPE_AGENT);
        int goal = (ticket / NBLK + 1) * NBLK;
        while (__hip_atomic_load(bar, __ATOMIC_ACQUIRE,
                                 __HIP_MEMORY_SCOPE_AGENT) < goal) {
            __builtin_amdgcn_s_sleep(2);
        }
    }
    __syncthreads();
}

// ---------------------------------------------------------------------------
// Prep: Wg[4m+g][k] = k<256 ? Wih[g*512+m][k] : Whh[g*512+m][k-256]
//       bg[4m+g]    = b_ih[g*512+m] + b_hh[g*512+m]
// ---------------------------------------------------------------------------
__global__ __launch_bounds__(256) void prep_wg(
    const float* __restrict__ Wih, const float* __restrict__ Whh,
    const float* __restrict__ bih, const float* __restrict__ bhh,
    float* __restrict__ Wg, float* __restrict__ bg)
{
    const int rp = blockIdx.x;          // 0..2047  (= 4*m + g)
    const int m = rp >> 2, g = rp & 3;
    const int row = g * 512 + m;
    for (int k = threadIdx.x; k < 768; k += 256)
        Wg[(size_t)rp * 768 + k] = (k < 256) ? Wih[(size_t)row * 256 + k]
                                             : Whh[(size_t)row * 512 + (k - 256)];
    if (threadIdx.x == 0) bg[rp] = bih[row] + bhh[row];
}

// We_p[q][s][j] = We_w[s][q*4+j]  (q=k/4, j=k%4): lane=s float4 loads coalesce
__global__ __launch_bounds__(256) void prep_wep(
    const float* __restrict__ We_w, float* __restrict__ We_p)
{
    int idx = blockIdx.x * 256 + threadIdx.x;   // < 131072
    int q = idx >> 9, rest = idx & 511, s = rest >> 2, j = rest & 3;
    We_p[idx] = We_w[s * 1024 + q * 4 + j];
}

// ---------------------------------------------------------------------------
// Precompute Ue_x[b,s,n] = sum_t x[t,b,n]*Ue_w[s,t] + Ue_b[s], layout (b,s,n)
// ---------------------------------------------------------------------------
__global__ __launch_bounds__(256) void ue_pre(
    const float* __restrict__ x, const float* __restrict__ Ue_w,
    const float* __restrict__ Ue_b, float* __restrict__ ue)
{
    const int b = blockIdx.y;
    const int s0 = blockIdx.x * 32;
    const int n = threadIdx.x;
    __shared__ float xs[32][256];
    __shared__ float uws[32][32];

    float acc[32];
#pragma unroll
    for (int i = 0; i < 32; i++) acc[i] = 0.f;

#pragma unroll 1
    for (int tc = 0; tc < 4; tc++) {
        __syncthreads();
#pragma unroll
        for (int tt = 0; tt < 32; tt++)
            xs[tt][n] = x[(size_t)(tc * 32 + tt) * (B_ * N_) + b * N_ + n];
#pragma unroll
        for (int q = 0; q < 4; q++) {
            int e = q * 256 + n;
            int s = e >> 5, tt = e & 31;
            uws[s][tt] = Ue_w[(s0 + s) * T_ + tc * 32 + tt];
        }
        __syncthreads();
        float xr[32];
#pragma unroll
        for (int tt = 0; tt < 32; tt++) xr[tt] = xs[tt][n];
#pragma unroll
        for (int s = 0; s < 32; s++) {
            float a = acc[s];
#pragma unroll
            for (int tt = 0; tt < 32; tt++) a += xr[tt] * uws[s][tt];
            acc[s] = a;
        }
    }
#pragma unroll
    for (int s = 0; s < 32; s++)
        ue[((size_t)b * T_ + s0 + s) * N_ + n] = acc[s] + Ue_b[s0 + s];
}

// ---------------------------------------------------------------------------
// Persistent scan: 128 steps in one regular kernel, hand-rolled grid barrier.
// Grid = 256 blocks x 256 threads, __launch_bounds__(256,2) guarantees
// device capacity 512 blocks >= grid, so all blocks are co-resident.
// Phase B' (block handles b=blk and b=blk+256): we=[h,c]@We^T+b; attn; xtil.
// Phase C (block = 64b x 64gc tile): gates GEMM + fused LSTM cell.
// ---------------------------------------------------------------------------
__global__ __launch_bounds__(256, 2) void scan_persist(
    const float* __restrict__ x, const float* __restrict__ h0,
    const float* __restrict__ We_p, const float* __restrict__ We_b,
    const float* __restrict__ ve_w, const float* __restrict__ ue,
    const float* __restrict__ Wg, const float* __restrict__ bg,
    float* __restrict__ cbuf, float* __restrict__ hseq,
    float* __restrict__ xtil, int* bar)
{
    const int tid = threadIdx.x;
    const int blk = blockIdx.x;

    __shared__ float hc[1024];
    __shared__ float wepart[256];
    __shared__ float we_s[128];
    __shared__ float ve_s[128];
    __shared__ float red[256];
    __shared__ float As[16][68];
    __shared__ float Ws[16][68];

    if (tid < 128) ve_s[tid] = ve_w[tid];

    // phase C tile constants (32 ctiles x 8 btiles = 256 blocks)
    const int ctile = blk & 31, btile = blk >> 5;
    const int col0 = ctile * 64, row0 = btile * 64;
    const int tx = tid & 15, ty = tid >> 4;
    const int li = tid >> 2;            // load row 0..63
    const int lk4 = (tid & 3) * 4;      // load k offset

#pragma unroll 1
    for (int t = 0; t < T_; t++) {
        const float* hprev = t ? (hseq + (size_t)(t - 1) * (B_ * M_)) : h0;

        // -------- Phase B': we + attention for b = blk and blk+256 --------
#pragma unroll 1
        for (int bb = 0; bb < 2; bb++) {
            const int b = blk + bb * 256;
            __syncthreads();
            float4 hv = (tid < 128)
                ? *(const float4*)&hprev[b * M_ + tid * 4]
                : *(const float4*)&cbuf[b * M_ + (tid - 128) * 4];
            *(float4*)&hc[tid * 4] = hv;
            __syncthreads();

            // we partial: threads 0-127 do k[0,512), 128-255 do k[512,1024)
            const int s = tid & 127;
            const int q0 = (tid >> 7) * 128;
            float wacc = 0.f;
#pragma unroll 4
            for (int q = q0; q < q0 + 128; q++) {
                float4 w = *(const float4*)&We_p[(size_t)q * 512 + s * 4];
                float4 h4 = *(const float4*)&hc[q * 4];
                wacc += w.x * h4.x + w.y * h4.y + w.z * h4.z + w.w * h4.w;
            }
            wepart[tid] = wacc;
            __syncthreads();
            if (tid < 128) we_s[tid] = wepart[tid] + wepart[tid + 128] + We_b[tid];
            __syncthreads();

            // attention: e[n] = sum_s tanh(we[s] + ue[b,s,n]) * ve[s]
            const int n = tid;
            const float* up = ue + (size_t)b * (T_ * N_) + n;
            float eacc = 0.f;
#pragma unroll 4
            for (int ss = 0; ss < 128; ss++)
                eacc += tanhf(we_s[ss] + up[ss * N_]) * ve_s[ss];

            red[n] = eacc; __syncthreads();
            for (int off = 128; off > 0; off >>= 1) {
                if (n < off) red[n] = fmaxf(red[n], red[n + off]);
                __syncthreads();
            }
            float mx = red[0]; __syncthreads();
            float ex = expf(eacc - mx);
            red[n] = ex; __syncthreads();
            for (int off = 128; off > 0; off >>= 1) {
                if (n < off) red[n] += red[n + off];
                __syncthreads();
            }
            float alpha = ex / red[0];
            xtil[b * N_ + n] = alpha * x[(size_t)t * (B_ * N_) + b * N_ + n];
        }
        grid_bar(bar);

        // -------- Phase C: gates GEMM (64x64 tile) + fused cell --------
        {
            float acc[4][4];
#pragma unroll
            for (int r = 0; r < 4; r++)
#pragma unroll
                for (int cc = 0; cc < 4; cc++) acc[r][cc] = 0.f;

#pragma unroll 1
            for (int pass = 0; pass < 2; pass++) {
                const float* A = pass ? hprev : xtil;
                const int lda = pass ? M_ : N_;
                const int K = pass ? 512 : 256;
                const float* W = Wg + (pass ? 256 : 0);
                float4 av = *(const float4*)&A[(size_t)(row0 + li) * lda + lk4];
                float4 wv = *(const float4*)&W[(size_t)(col0 + li) * 768 + lk4];
#pragma unroll 1
                for (int kk = 0; kk < K; kk += 16) {
                    __syncthreads();
                    As[lk4 + 0][li] = av.x; As[lk4 + 1][li] = av.y;
                    As[lk4 + 2][li] = av.z; As[lk4 + 3][li] = av.w;
                    Ws[lk4 + 0][li] = wv.x; Ws[lk4 + 1][li] = wv.y;
                    Ws[lk4 + 2][li] = wv.z; Ws[lk4 + 3][li] = wv.w;
                    __syncthreads();
                    if (kk + 16 < K) {
                        av = *(const float4*)&A[(size_t)(row0 + li) * lda + kk + 16 + lk4];
                        wv = *(const float4*)&W[(size_t)(col0 + li) * 768 + kk + 16 + lk4];
                    }
#pragma unroll
                    for (int k = 0; k < 16; k++) {
                        float4 a = *(const float4*)&As[k][ty * 4];
                        float4 w = *(const float4*)&Ws[k][tx * 4];
                        acc[0][0] += a.x * w.x; acc[0][1] += a.x * w.y;
                        acc[0][2] += a.x * w.z; acc[0][3] += a.x * w.w;
                        acc[1][0] += a.y * w.x; acc[1][1] += a.y * w.y;
                        acc[1][2] += a.y * w.z; acc[1][3] += a.y * w.w;
                        acc[2][0] += a.z * w.x; acc[2][1] += a.z * w.y;
                        acc[2][2] += a.z * w.z; acc[2][3] += a.z * w.w;
                        acc[3][0] += a.w * w.x; acc[3][1] += a.w * w.y;
                        acc[3][2] += a.w * w.z; acc[3][3] += a.w * w.w;
                    }
                }
            }

            // fused LSTM cell: thread owns m = col0/4 + tx, rows row0+ty*4+r
            const int m = (col0 >> 2) + tx;
            const float bi  = bg[col0 + tx * 4 + 0];
            const float bf  = bg[col0 + tx * 4 + 1];
            const float bgg = bg[col0 + tx * 4 + 2];
            const float bo  = bg[col0 + tx * 4 + 3];
            float* hseq_t = hseq + (size_t)t * (B_ * M_);
#pragma unroll
            for (int r = 0; r < 4; r++) {
                const int b = row0 + ty * 4 + r;
                const int idx = b * M_ + m;
                float gi = acc[r][0] + bi;
                float gf = acc[r][1] + bf;
                float gc = acc[r][2] + bgg;
                float go = acc[r][3] + bo;
                float si = 1.f / (1.f + expf(-gi));
                float sf = 1.f / (1.f + expf(-gf));
                float so = 1.f / (1.f + expf(-go));
                float cn = sf * cbuf[idx] + si * tanhf(gc);
                cbuf[idx] = cn;
                hseq_t[idx] = so * tanhf(cn);
            }
        }
        grid_bar(bar);
    }
}

// ---------------------------------------------------------------------------
// Post: l[b,t] += sum_m tanh(h_seq@Ud_w^T + Ud_b)*vd_w   (rows=T*B, cols=M)
// ---------------------------------------------------------------------------
__global__ __launch_bounds__(256) void gemm_l(
    const float* __restrict__ A1,
    const float* __restrict__ W1,
    const float* __restrict__ bias1,
    const float* __restrict__ vw, float* __restrict__ lout)
{
    __shared__ float As[16][68];
    __shared__ float Ws[16][68];
    __shared__ float rsum[64];

    const int tid = threadIdx.x;
    const int tx = tid & 15, ty = tid >> 4;
    const int row0 = blockIdx.y * 64;
    const int col0 = blockIdx.x * 64;
    const int li = tid >> 2;
    const int lk4 = (tid & 3) * 4;

    float acc[4][4];
#pragma unroll
    for (int r = 0; r < 4; r++)
#pragma unroll
        for (int cc = 0; cc < 4; cc++) acc[r][cc] = 0.f;

    float4 av = *(const float4*)&A1[(size_t)(row0 + li) * M_ + lk4];
    float4 wv = *(const float4*)&W1[(size_t)(col0 + li) * M_ + lk4];
#pragma unroll 1
    for (int kk = 0; kk < 512; kk += 16) {
        __syncthreads();
        As[lk4 + 0][li] = av.x; As[lk4 + 1][li] = av.y;
        As[lk4 + 2][li] = av.z; As[lk4 + 3][li] = av.w;
        Ws[lk4 + 0][li] = wv.x; Ws[lk4 + 1][li] = wv.y;
        Ws[lk4 + 2][li] = wv.z; Ws[lk4 + 3][li] = wv.w;
        __syncthreads();
        if (kk + 16 < 512) {
            av = *(const float4*)&A1[(size_t)(row0 + li) * M_ + kk + 16 + lk4];
            wv = *(const float4*)&W1[(size_t)(col0 + li) * M_ + kk + 16 + lk4];
        }
#pragma unroll
        for (int k = 0; k < 16; k++) {
            float4 a = *(const float4*)&As[k][ty * 4];
            float4 w = *(const float4*)&Ws[k][tx * 4];
            acc[0][0] += a.x * w.x; acc[0][1] += a.x * w.y;
            acc[0][2] += a.x * w.z; acc[0][3] += a.x * w.w;
            acc[1][0] += a.y * w.x; acc[1][1] += a.y * w.y;
            acc[1][2] += a.y * w.z; acc[1][3] += a.y * w.w;
            acc[2][0] += a.z * w.x; acc[2][1] += a.z * w.y;
            acc[2][2] += a.z * w.z; acc[2][3] += a.z * w.w;
            acc[3][0] += a.w * w.x; acc[3][1] += a.w * w.y;
            acc[3][2] += a.w * w.z; acc[3][3] += a.w * w.w;
        }
    }

    __syncthreads();
    if (tid < 64) rsum[tid] = 0.f;
    __syncthreads();
    float part[4] = {0.f, 0.f, 0.f, 0.f};
#pragma unroll
    for (int r = 0; r < 4; r++)
#pragma unroll
        for (int cc = 0; cc < 4; cc++) {
            int gc = col0 + tx * 4 + cc;
            part[r] += tanhf(acc[r][cc] + bias1[gc]) * vw[gc];
        }
#pragma unroll
    for (int r = 0; r < 4; r++)
        atomicAdd(&rsum[ty * 4 + r], part[r]);
    __syncthreads();
    if (tid < 64) {
        int gr = row0 + tid;          // gr = t*512 + b
        int b = gr & 511, t = gr >> 9;
        atomicAdd(&lout[b * 128 + t], rsum[tid]);
    }
}

// ---------------------------------------------------------------------------
// Final: beta = softmax_t(l); ctx = sum_t beta*h_seq; logits = ctx.out_w+out_b
// ---------------------------------------------------------------------------
__global__ __launch_bounds__(512) void final_kernel(
    const float* __restrict__ lbuf, const float* __restrict__ hseq,
    const float* __restrict__ out_w, const float* __restrict__ out_b,
    float* __restrict__ out)
{
    const int b = blockIdx.x;
    const int tid = threadIdx.x;
    __shared__ float beta_s[128];
    __shared__ float red[512];

    float lv = (tid < 128) ? lbuf[b * 128 + tid] : -1e30f;
    red[tid] = lv; __syncthreads();
    for (int off = 256; off >= 1; off >>= 1) {
        if (tid < off) red[tid] = fmaxf(red[tid], red[tid + off]);
        __syncthreads();
    }
    float mx = red[0]; __syncthreads();
    float ex = (tid < 128) ? expf(lv - mx) : 0.f;
    red[tid] = ex; __syncthreads();
    for (int off = 256; off >= 1; off >>= 1) {
        if (tid < off) red[tid] += red[tid + off];
        __syncthreads();
    }
    float denom = red[0];
    if (tid < 128) {
        float bt = ex / denom;
        beta_s[tid] = bt;
        out[512 + b * 128 + tid] = bt;
    }
    __syncthreads();

    float ctx = 0.f;
#pragma unroll 4
    for (int t = 0; t < 128; t++)
        ctx += beta_s[t] * hseq[(size_t)t * (B_ * M_) + b * M_ + tid];

    red[tid] = ctx * out_w[tid]; __syncthreads();
    for (int off = 256; off >= 1; off >>= 1) {
        if (tid < off) red[tid] += red[tid + off];
        __syncthreads();
    }
    if (tid == 0) out[b] = red[0] + out_b[0];
}

// ---------------------------------------------------------------------------
extern "C" void kernel_launch(void* const* d_in, const int* in_sizes, int n_in,
                              void* d_out, int out_size, void* d_ws, size_t ws_size,
                              hipStream_t stream)
{
    const float* x    = (const float*)d_in[0];
    const float* h0   = (const float*)d_in[1];
    const float* c0   = (const float*)d_in[2];
    const float* Wih  = (const float*)d_in[3];
    const float* Whh  = (const float*)d_in[4];
    const float* b_ih = (const float*)d_in[5];
    const float* b_hh = (const float*)d_in[6];
    const float* We_w = (const float*)d_in[7];
    const float* We_b = (const float*)d_in[8];
    const float* Ue_w = (const float*)d_in[9];
    const float* Ue_b = (const float*)d_in[10];
    const float* ve_w = (const float*)d_in[11];
    const float* Ud_w = (const float*)d_in[13];
    const float* Ud_b = (const float*)d_in[14];
    const float* vd_w = (const float*)d_in[15];
    const float* out_w = (const float*)d_in[17];
    const float* out_b = (const float*)d_in[18];
    float* out = (float*)d_out;

    // workspace layout (floats). lbuf aliases xt (disjoint lifetimes).
    float* ws    = (float*)d_ws;
    float* ue    = ws;                       // 16,777,216  (B*T*N)
    float* hseq  = ue + 16777216;            // 33,554,432  (T*B*M)
    float* cbuf  = hseq + 33554432;          //    262,144  (B*M)
    float* xt    = cbuf + 262144;            //    131,072  (B*N)  [scan only]
    float* lbuf  = xt;                       //     65,536  (B*T)  [post only]
    float* Wg    = xt + 131072;              //  1,572,864  (2048*768)
    float* bgv   = Wg + 1572864;             //      2,048
    float* We_p  = bgv + 2048;               //    131,072  (256*128*4)
    int*   bar   = (int*)(We_p + 131072);    //         16

    hipMemcpyAsync(cbuf, c0, (size_t)B_ * M_ * 4, hipMemcpyDeviceToDevice, stream);
    hipMemsetAsync(bar, 0, 16, stream);

    prep_wg<<<2048, 256, 0, stream>>>(Wih, Whh, b_ih, b_hh, Wg, bgv);
    prep_wep<<<512, 256, 0, stream>>>(We_w, We_p);
    ue_pre<<<dim3(4, 512), 256, 0, stream>>>(x, Ue_w, Ue_b, ue);

    scan_persist<<<NBLK, 256, 0, stream>>>(
        x, h0, We_p, We_b, ve_w, ue, Wg, bgv, cbuf, hseq, xt, bar);

    hipMemsetAsync(lbuf, 0, (size_t)B_ * T_ * 4, stream);
    gemm_l<<<dim3(8, 1024), 256, 0, stream>>>(hseq, Ud_w, Ud_b, vd_w, lbuf);
    final_kernel<<<512, 512, 0, stream>>>(lbuf, hseq, out_w, out_b, out);
}

// Round 5
// 11931.566 us; speedup vs baseline: 2.1188x; 2.1188x over previous
//
#include <hip/hip_runtime.h>
#include <math.h>

// Problem dims
#define T_ 128
#define B_ 512
#define N_ 256
#define M_ 512
#define G_ 2048   // 4*M
#define NBLK 256  // 8 groups x 32 blocks
#define GSZ 32    // blocks per group

// ---------------------------------------------------------------------------
// Device-coherent (MALL-level) scalar access, relaxed: emits sc1 load/store
// with NO cache writeback/invalidate -> weights stay hot in per-XCD L2.
// ---------------------------------------------------------------------------
__device__ __forceinline__ float ld_dev(const float* p) {
    return __hip_atomic_load(const_cast<float*>(p), __ATOMIC_RELAXED,
                             __HIP_MEMORY_SCOPE_AGENT);
}
__device__ __forceinline__ void st_dev(float* p, float v) {
    __hip_atomic_store(p, v, __ATOMIC_RELAXED, __HIP_MEMORY_SCOPE_AGENT);
}

// Fast transcendentals (abs err ~1e-6, threshold is 1e-3)
__device__ __forceinline__ float fast_tanh(float x) {
    float e = __expf(2.f * x);
    return 1.f - __fdividef(2.f, e + 1.f);
}
__device__ __forceinline__ float fast_sig(float x) {
    return __fdividef(1.f, 1.f + __expf(-x));
}

// ---------------------------------------------------------------------------
// Group barrier: 32 blocks, relaxed ticket. __syncthreads drains vmcnt(0)
// for every wave (m97), so all sc1 stores are globally visible before the
// ticket increment. No acq/rel -> no L2 flush.
// ---------------------------------------------------------------------------
__device__ __forceinline__ void group_bar(int* gbar, int goal) {
    __syncthreads();
    if (threadIdx.x == 0) {
        asm volatile("s_waitcnt vmcnt(0)" ::: "memory");
        __hip_atomic_fetch_add(gbar, 1, __ATOMIC_RELAXED,
                               __HIP_MEMORY_SCOPE_AGENT);
        while (__hip_atomic_load(gbar, __ATOMIC_RELAXED,
                                 __HIP_MEMORY_SCOPE_AGENT) < goal) {
            __builtin_amdgcn_s_sleep(1);
        }
    }
    __syncthreads();
}

// ---------------------------------------------------------------------------
// Prep: Wg[4m+g][k] = k<256 ? Wih[g*512+m][k] : Whh[g*512+m][k-256]
//       bg[4m+g]    = b_ih[g*512+m] + b_hh[g*512+m]
// ---------------------------------------------------------------------------
__global__ __launch_bounds__(256) void prep_wg(
    const float* __restrict__ Wih, const float* __restrict__ Whh,
    const float* __restrict__ bih, const float* __restrict__ bhh,
    float* __restrict__ Wg, float* __restrict__ bg)
{
    const int rp = blockIdx.x;          // 0..2047  (= 4*m + g)
    const int m = rp >> 2, g = rp & 3;
    const int row = g * 512 + m;
    for (int k = threadIdx.x; k < 768; k += 256)
        Wg[(size_t)rp * 768 + k] = (k < 256) ? Wih[(size_t)row * 256 + k]
                                             : Whh[(size_t)row * 512 + (k - 256)];
    if (threadIdx.x == 0) bg[rp] = bih[row] + bhh[row];
}

// We_p[q][s][j] = We_w[s][q*4+j]  (q=k/4, j=k%4): lane=s float4 loads coalesce
__global__ __launch_bounds__(256) void prep_wep(
    const float* __restrict__ We_w, float* __restrict__ We_p)
{
    int idx = blockIdx.x * 256 + threadIdx.x;   // < 131072
    int q = idx >> 9, rest = idx & 511, s = rest >> 2, j = rest & 3;
    We_p[idx] = We_w[s * 1024 + q * 4 + j];
}

// ---------------------------------------------------------------------------
// Precompute Ue_x[b,s,n] = sum_t x[t,b,n]*Ue_w[s,t] + Ue_b[s], layout (b,s,n)
// ---------------------------------------------------------------------------
__global__ __launch_bounds__(256) void ue_pre(
    const float* __restrict__ x, const float* __restrict__ Ue_w,
    const float* __restrict__ Ue_b, float* __restrict__ ue)
{
    const int b = blockIdx.y;
    const int s0 = blockIdx.x * 32;
    const int n = threadIdx.x;
    __shared__ float xs[32][256];
    __shared__ float uws[32][32];

    float acc[32];
#pragma unroll
    for (int i = 0; i < 32; i++) acc[i] = 0.f;

#pragma unroll 1
    for (int tc = 0; tc < 4; tc++) {
        __syncthreads();
#pragma unroll
        for (int tt = 0; tt < 32; tt++)
            xs[tt][n] = x[(size_t)(tc * 32 + tt) * (B_ * N_) + b * N_ + n];
#pragma unroll
        for (int q = 0; q < 4; q++) {
            int e = q * 256 + n;
            int s = e >> 5, tt = e & 31;
            uws[s][tt] = Ue_w[(s0 + s) * T_ + tc * 32 + tt];
        }
        __syncthreads();
        float xr[32];
#pragma unroll
        for (int tt = 0; tt < 32; tt++) xr[tt] = xs[tt][n];
#pragma unroll
        for (int s = 0; s < 32; s++) {
            float a = acc[s];
#pragma unroll
            for (int tt = 0; tt < 32; tt++) a += xr[tt] * uws[s][tt];
            acc[s] = a;
        }
    }
#pragma unroll
    for (int s = 0; s < 32; s++)
        ue[((size_t)b * T_ + s0 + s) * N_ + n] = acc[s] + Ue_b[s0 + s];
}

// ---------------------------------------------------------------------------
// Persistent scan, group-local communication only.
// Group g = blocks [g*32, g*32+32) owns batches [g*64, g*64+64).
// Part A (block sg in group): batches bA=g*64+sg*2, bB=bA+1:
//   we=[h,c]@We^T+b (one We_p stream for both batches); attn softmax; xtil.
// Part C: gates GEMM rows [g*64,+64) x cols [sg*64,+64) + fused LSTM cell.
// Cross-block arrays (xtil, cbuf, hseq) accessed sc1; weights plain (L2-hot).
// ---------------------------------------------------------------------------
__global__ __launch_bounds__(256, 2) void scan_persist(
    const float* __restrict__ x, const float* __restrict__ h0,
    const float* __restrict__ We_p, const float* __restrict__ We_b,
    const float* __restrict__ ve_w, const float* __restrict__ ue,
    const float* __restrict__ Wg, const float* __restrict__ bg,
    float* __restrict__ cbuf, float* __restrict__ hseq,
    float* __restrict__ xtil, int* bar)
{
    const int tid = threadIdx.x;
    const int blk = blockIdx.x;
    const int g = blk >> 5;          // group 0..7
    const int sg = blk & 31;         // slot in group 0..31
    int* gbar = bar + g * 32;        // 128B-spaced counters

    __shared__ float hcA[1024];
    __shared__ float hcB[1024];
    __shared__ float wepartA[256];
    __shared__ float wepartB[256];
    __shared__ float weA[128];
    __shared__ float weB[128];
    __shared__ float ve_s[128];
    __shared__ float red[256];
    __shared__ float As[16][68];
    __shared__ float Ws[16][68];

    if (tid < 128) ve_s[tid] = ve_w[tid];

    // part A batches
    const int bA = g * 64 + sg * 2;
    const int bB = bA + 1;
    // part C tile
    const int row0 = g * 64, col0 = sg * 64;
    const int tx = tid & 15, ty = tid >> 4;
    const int li = tid >> 2;            // load row 0..63
    const int lk4 = (tid & 3) * 4;      // load k offset

#pragma unroll 1
    for (int t = 0; t < T_; t++) {
        const float* hprev = t ? (hseq + (size_t)(t - 1) * (B_ * M_)) : h0;

        // -------- Part A: we + attention for bA, bB --------
        {
#pragma unroll
            for (int j = 0; j < 4; j++) {
                int idx = tid + j * 256;     // 0..1023
                float vA = (idx < 512) ? ld_dev(hprev + bA * M_ + idx)
                                       : ld_dev(cbuf + bA * M_ + idx - 512);
                float vB = (idx < 512) ? ld_dev(hprev + bB * M_ + idx)
                                       : ld_dev(cbuf + bB * M_ + idx - 512);
                hcA[idx] = vA; hcB[idx] = vB;
            }
            __syncthreads();

            // we partials: thread = (s, half); one We_p stream, 2 batches
            const int s = tid & 127;
            const int q0 = (tid >> 7) * 128;
            float accA = 0.f, accB = 0.f;
#pragma unroll 4
            for (int q = q0; q < q0 + 128; q++) {
                float4 w = *(const float4*)&We_p[(size_t)q * 512 + s * 4];
                float4 a = *(const float4*)&hcA[q * 4];
                float4 b2 = *(const float4*)&hcB[q * 4];
                accA += w.x * a.x + w.y * a.y + w.z * a.z + w.w * a.w;
                accB += w.x * b2.x + w.y * b2.y + w.z * b2.z + w.w * b2.w;
            }
            wepartA[tid] = accA; wepartB[tid] = accB;
            __syncthreads();
            if (tid < 128) {
                float wb = We_b[tid];
                weA[tid] = wepartA[tid] + wepartA[tid + 128] + wb;
                weB[tid] = wepartB[tid] + wepartB[tid + 128] + wb;
            }
            __syncthreads();

            // attention per batch
#pragma unroll 1
            for (int bb = 0; bb < 2; bb++) {
                const int b = bb ? bB : bA;
                const float* wes = bb ? weB : weA;
                const int n = tid;
                const float* up = ue + (size_t)b * (T_ * N_) + n;
                float eacc = 0.f;
#pragma unroll 4
                for (int ss = 0; ss < 128; ss++)
                    eacc += fast_tanh(wes[ss] + up[ss * N_]) * ve_s[ss];

                red[n] = eacc; __syncthreads();
                for (int off = 128; off > 0; off >>= 1) {
                    if (n < off) red[n] = fmaxf(red[n], red[n + off]);
                    __syncthreads();
                }
                float mx = red[0]; __syncthreads();
                float ex = __expf(eacc - mx);
                red[n] = ex; __syncthreads();
                for (int off = 128; off > 0; off >>= 1) {
                    if (n < off) red[n] += red[n + off];
                    __syncthreads();
                }
                float alpha = __fdividef(ex, red[0]);
                st_dev(&xtil[b * N_ + n],
                       alpha * x[(size_t)t * (B_ * N_) + b * N_ + n]);
                __syncthreads();
            }
        }
        group_bar(gbar, (t * 2 + 1) * GSZ);

        // -------- Part C: gates GEMM (64x64 tile) + fused cell --------
        {
            float acc[4][4];
#pragma unroll
            for (int r = 0; r < 4; r++)
#pragma unroll
                for (int cc = 0; cc < 4; cc++) acc[r][cc] = 0.f;

#pragma unroll 1
            for (int pass = 0; pass < 2; pass++) {
                const float* A = pass ? hprev : xtil;
                const int lda = pass ? M_ : N_;
                const int K = pass ? 512 : 256;
                const float* W = Wg + (pass ? 256 : 0);
                const float* arow = A + (size_t)(row0 + li) * lda + lk4;
                float a0 = ld_dev(arow + 0), a1 = ld_dev(arow + 1);
                float a2 = ld_dev(arow + 2), a3 = ld_dev(arow + 3);
                float4 wv = *(const float4*)&W[(size_t)(col0 + li) * 768 + lk4];
#pragma unroll 1
                for (int kk = 0; kk < K; kk += 16) {
                    __syncthreads();
                    As[lk4 + 0][li] = a0; As[lk4 + 1][li] = a1;
                    As[lk4 + 2][li] = a2; As[lk4 + 3][li] = a3;
                    Ws[lk4 + 0][li] = wv.x; Ws[lk4 + 1][li] = wv.y;
                    Ws[lk4 + 2][li] = wv.z; Ws[lk4 + 3][li] = wv.w;
                    __syncthreads();
                    if (kk + 16 < K) {
                        a0 = ld_dev(arow + kk + 16);
                        a1 = ld_dev(arow + kk + 17);
                        a2 = ld_dev(arow + kk + 18);
                        a3 = ld_dev(arow + kk + 19);
                        wv = *(const float4*)&W[(size_t)(col0 + li) * 768 + kk + 16 + lk4];
                    }
#pragma unroll
                    for (int k = 0; k < 16; k++) {
                        float4 a = *(const float4*)&As[k][ty * 4];
                        float4 w = *(const float4*)&Ws[k][tx * 4];
                        acc[0][0] += a.x * w.x; acc[0][1] += a.x * w.y;
                        acc[0][2] += a.x * w.z; acc[0][3] += a.x * w.w;
                        acc[1][0] += a.y * w.x; acc[1][1] += a.y * w.y;
                        acc[1][2] += a.y * w.z; acc[1][3] += a.y * w.w;
                        acc[2][0] += a.z * w.x; acc[2][1] += a.z * w.y;
                        acc[2][2] += a.z * w.z; acc[2][3] += a.z * w.w;
                        acc[3][0] += a.w * w.x; acc[3][1] += a.w * w.y;
                        acc[3][2] += a.w * w.z; acc[3][3] += a.w * w.w;
                    }
                }
            }

            // fused LSTM cell: thread owns m = col0/4 + tx, rows row0+ty*4+r
            const int m = (col0 >> 2) + tx;
            const float bi  = bg[col0 + tx * 4 + 0];
            const float bf  = bg[col0 + tx * 4 + 1];
            const float bgg = bg[col0 + tx * 4 + 2];
            const float bo  = bg[col0 + tx * 4 + 3];
            float* hseq_t = hseq + (size_t)t * (B_ * M_);
#pragma unroll
            for (int r = 0; r < 4; r++) {
                const int b = row0 + ty * 4 + r;
                const int idx = b * M_ + m;
                float gi = acc[r][0] + bi;
                float gf = acc[r][1] + bf;
                float gc = acc[r][2] + bgg;
                float go = acc[r][3] + bo;
                float cn = fast_sig(gf) * ld_dev(&cbuf[idx])
                         + fast_sig(gi) * fast_tanh(gc);
                st_dev(&cbuf[idx], cn);
                st_dev(&hseq_t[idx], fast_sig(go) * fast_tanh(cn));
            }
        }
        group_bar(gbar, (t * 2 + 2) * GSZ);
    }
}

// ---------------------------------------------------------------------------
// Post: l[b,t] += sum_m tanh(h_seq@Ud_w^T + Ud_b)*vd_w   (rows=T*B, cols=M)
// ---------------------------------------------------------------------------
__global__ __launch_bounds__(256) void gemm_l(
    const float* __restrict__ A1,
    const float* __restrict__ W1,
    const float* __restrict__ bias1,
    const float* __restrict__ vw, float* __restrict__ lout)
{
    __shared__ float As[16][68];
    __shared__ float Ws[16][68];
    __shared__ float rsum[64];

    const int tid = threadIdx.x;
    const int tx = tid & 15, ty = tid >> 4;
    const int row0 = blockIdx.y * 64;
    const int col0 = blockIdx.x * 64;
    const int li = tid >> 2;
    const int lk4 = (tid & 3) * 4;

    float acc[4][4];
#pragma unroll
    for (int r = 0; r < 4; r++)
#pragma unroll
        for (int cc = 0; cc < 4; cc++) acc[r][cc] = 0.f;

    float4 av = *(const float4*)&A1[(size_t)(row0 + li) * M_ + lk4];
    float4 wv = *(const float4*)&W1[(size_t)(col0 + li) * M_ + lk4];
#pragma unroll 1
    for (int kk = 0; kk < 512; kk += 16) {
        __syncthreads();
        As[lk4 + 0][li] = av.x; As[lk4 + 1][li] = av.y;
        As[lk4 + 2][li] = av.z; As[lk4 + 3][li] = av.w;
        Ws[lk4 + 0][li] = wv.x; Ws[lk4 + 1][li] = wv.y;
        Ws[lk4 + 2][li] = wv.z; Ws[lk4 + 3][li] = wv.w;
        __syncthreads();
        if (kk + 16 < 512) {
            av = *(const float4*)&A1[(size_t)(row0 + li) * M_ + kk + 16 + lk4];
            wv = *(const float4*)&W1[(size_t)(col0 + li) * M_ + kk + 16 + lk4];
        }
#pragma unroll
        for (int k = 0; k < 16; k++) {
            float4 a = *(const float4*)&As[k][ty * 4];
            float4 w = *(const float4*)&Ws[k][tx * 4];
            acc[0][0] += a.x * w.x; acc[0][1] += a.x * w.y;
            acc[0][2] += a.x * w.z; acc[0][3] += a.x * w.w;
            acc[1][0] += a.y * w.x; acc[1][1] += a.y * w.y;
            acc[1][2] += a.y * w.z; acc[1][3] += a.y * w.w;
            acc[2][0] += a.z * w.x; acc[2][1] += a.z * w.y;
            acc[2][2] += a.z * w.z; acc[2][3] += a.z * w.w;
            acc[3][0] += a.w * w.x; acc[3][1] += a.w * w.y;
            acc[3][2] += a.w * w.z; acc[3][3] += a.w * w.w;
        }
    }

    __syncthreads();
    if (tid < 64) rsum[tid] = 0.f;
    __syncthreads();
    float part[4] = {0.f, 0.f, 0.f, 0.f};
#pragma unroll
    for (int r = 0; r < 4; r++)
#pragma unroll
        for (int cc = 0; cc < 4; cc++) {
            int gc = col0 + tx * 4 + cc;
            part[r] += fast_tanh(acc[r][cc] + bias1[gc]) * vw[gc];
        }
#pragma unroll
    for (int r = 0; r < 4; r++)
        atomicAdd(&rsum[ty * 4 + r], part[r]);
    __syncthreads();
    if (tid < 64) {
        int gr = row0 + tid;          // gr = t*512 + b
        int b = gr & 511, t = gr >> 9;
        atomicAdd(&lout[b * 128 + t], rsum[tid]);
    }
}

// ---------------------------------------------------------------------------
// Final: beta = softmax_t(l); ctx = sum_t beta*h_seq; logits = ctx.out_w+out_b
// ---------------------------------------------------------------------------
__global__ __launch_bounds__(512) void final_kernel(
    const float* __restrict__ lbuf, const float* __restrict__ hseq,
    const float* __restrict__ out_w, const float* __restrict__ out_b,
    float* __restrict__ out)
{
    const int b = blockIdx.x;
    const int tid = threadIdx.x;
    __shared__ float beta_s[128];
    __shared__ float red[512];

    float lv = (tid < 128) ? lbuf[b * 128 + tid] : -1e30f;
    red[tid] = lv; __syncthreads();
    for (int off = 256; off >= 1; off >>= 1) {
        if (tid < off) red[tid] = fmaxf(red[tid], red[tid + off]);
        __syncthreads();
    }
    float mx = red[0]; __syncthreads();
    float ex = (tid < 128) ? __expf(lv - mx) : 0.f;
    red[tid] = ex; __syncthreads();
    for (int off = 256; off >= 1; off >>= 1) {
        if (tid < off) red[tid] += red[tid + off];
        __syncthreads();
    }
    float denom = red[0];
    if (tid < 128) {
        float bt = ex / denom;
        beta_s[tid] = bt;
        out[512 + b * 128 + tid] = bt;
    }
    __syncthreads();

    float ctx = 0.f;
#pragma unroll 4
    for (int t = 0; t < 128; t++)
        ctx += beta_s[t] * hseq[(size_t)t * (B_ * M_) + b * M_ + tid];

    red[tid] = ctx * out_w[tid]; __syncthreads();
    for (int off = 256; off >= 1; off >>= 1) {
        if (tid < off) red[tid] += red[tid + off];
        __syncthreads();
    }
    if (tid == 0) out[b] = red[0] + out_b[0];
}

// ---------------------------------------------------------------------------
extern "C" void kernel_launch(void* const* d_in, const int* in_sizes, int n_in,
                              void* d_out, int out_size, void* d_ws, size_t ws_size,
                              hipStream_t stream)
{
    const float* x    = (const float*)d_in[0];
    const float* h0   = (const float*)d_in[1];
    const float* c0   = (const float*)d_in[2];
    const float* Wih  = (const float*)d_in[3];
    const float* Whh  = (const float*)d_in[4];
    const float* b_ih = (const float*)d_in[5];
    const float* b_hh = (const float*)d_in[6];
    const float* We_w = (const float*)d_in[7];
    const float* We_b = (const float*)d_in[8];
    const float* Ue_w = (const float*)d_in[9];
    const float* Ue_b = (const float*)d_in[10];
    const float* ve_w = (const float*)d_in[11];
    const float* Ud_w = (const float*)d_in[13];
    const float* Ud_b = (const float*)d_in[14];
    const float* vd_w = (const float*)d_in[15];
    const float* out_w = (const float*)d_in[17];
    const float* out_b = (const float*)d_in[18];
    float* out = (float*)d_out;

    // workspace layout (floats). lbuf aliases xt (disjoint lifetimes).
    float* ws    = (float*)d_ws;
    float* ue    = ws;                       // 16,777,216  (B*T*N)
    float* hseq  = ue + 16777216;            // 33,554,432  (T*B*M)
    float* cbuf  = hseq + 33554432;          //    262,144  (B*M)
    float* xt    = cbuf + 262144;            //    131,072  (B*N)  [scan only]
    float* lbuf  = xt;                       //     65,536  (B*T)  [post only]
    float* Wg    = xt + 131072;              //  1,572,864  (2048*768)
    float* bgv   = Wg + 1572864;             //      2,048
    float* We_p  = bgv + 2048;               //    131,072  (256*128*4)
    int*   bar   = (int*)(We_p + 131072);    //   8*32 ints

    hipMemcpyAsync(cbuf, c0, (size_t)B_ * M_ * 4, hipMemcpyDeviceToDevice, stream);
    hipMemsetAsync(bar, 0, 8 * 32 * 4, stream);

    prep_wg<<<2048, 256, 0, stream>>>(Wih, Whh, b_ih, b_hh, Wg, bgv);
    prep_wep<<<512, 256, 0, stream>>>(We_w, We_p);
    ue_pre<<<dim3(4, 512), 256, 0, stream>>>(x, Ue_w, Ue_b, ue);

    scan_persist<<<NBLK, 256, 0, stream>>>(
        x, h0, We_p, We_b, ve_w, ue, Wg, bgv, cbuf, hseq, xt, bar);

    hipMemsetAsync(lbuf, 0, (size_t)B_ * T_ * 4, stream);
    gemm_l<<<dim3(8, 1024), 256, 0, stream>>>(hseq, Ud_w, Ud_b, vd_w, lbuf);
    final_kernel<<<512, 512, 0, stream>>>(lbuf, hseq, out_w, out_b, out);
}

// Round 6
// 9563.673 us; speedup vs baseline: 2.6435x; 1.2476x over previous
//
#include <hip/hip_runtime.h>
#include <math.h>

// Problem dims
#define T_ 128
#define B_ 512
#define N_ 256
#define M_ 512
#define G_ 2048   // 4*M
#define NBLK 256  // 8 groups x 32 blocks, 1 block/CU, 512 threads = 8 waves/CU
#define GSZ 32    // blocks per group

// ---------------------------------------------------------------------------
// Device-coherent scalar access, relaxed (sc1): no cache flush, cross-XCD safe
// ---------------------------------------------------------------------------
__device__ __forceinline__ float ld_dev(const float* p) {
    return __hip_atomic_load(const_cast<float*>(p), __ATOMIC_RELAXED,
                             __HIP_MEMORY_SCOPE_AGENT);
}
__device__ __forceinline__ void st_dev(float* p, float v) {
    __hip_atomic_store(p, v, __ATOMIC_RELAXED, __HIP_MEMORY_SCOPE_AGENT);
}

// Fast transcendentals (abs err ~1e-6, threshold 1e-3)
__device__ __forceinline__ float fast_tanh(float x) {
    float e = __expf(2.f * x);
    return 1.f - __fdividef(2.f, e + 1.f);
}
__device__ __forceinline__ float fast_sig(float x) {
    return __fdividef(1.f, 1.f + __expf(-x));
}

// ---------------------------------------------------------------------------
// Group barrier: 32 blocks, relaxed ticket, no L2 flush.
// ---------------------------------------------------------------------------
__device__ __forceinline__ void group_bar(int* gbar, int goal) {
    __syncthreads();
    if (threadIdx.x == 0) {
        asm volatile("s_waitcnt vmcnt(0)" ::: "memory");
        __hip_atomic_fetch_add(gbar, 1, __ATOMIC_RELAXED,
                               __HIP_MEMORY_SCOPE_AGENT);
        while (__hip_atomic_load(gbar, __ATOMIC_RELAXED,
                                 __HIP_MEMORY_SCOPE_AGENT) < goal) {
            __builtin_amdgcn_s_sleep(1);
        }
    }
    __syncthreads();
}

// ---------------------------------------------------------------------------
// Prep: Wg[4m+g][k] = k<256 ? Wih[g*512+m][k] : Whh[g*512+m][k-256]
// ---------------------------------------------------------------------------
__global__ __launch_bounds__(256) void prep_wg(
    const float* __restrict__ Wih, const float* __restrict__ Whh,
    const float* __restrict__ bih, const float* __restrict__ bhh,
    float* __restrict__ Wg, float* __restrict__ bg)
{
    const int rp = blockIdx.x;          // 0..2047  (= 4*m + g)
    const int m = rp >> 2, g = rp & 3;
    const int row = g * 512 + m;
    for (int k = threadIdx.x; k < 768; k += 256)
        Wg[(size_t)rp * 768 + k] = (k < 256) ? Wih[(size_t)row * 256 + k]
                                             : Whh[(size_t)row * 512 + (k - 256)];
    if (threadIdx.x == 0) bg[rp] = bih[row] + bhh[row];
}

// We_p[q][s][j] = We_w[s][q*4+j]
__global__ __launch_bounds__(256) void prep_wep(
    const float* __restrict__ We_w, float* __restrict__ We_p)
{
    int idx = blockIdx.x * 256 + threadIdx.x;   // < 131072
    int q = idx >> 9, rest = idx & 511, s = rest >> 2, j = rest & 3;
    We_p[idx] = We_w[s * 1024 + q * 4 + j];
}

// ---------------------------------------------------------------------------
// Precompute Ue_x[b,s,n] layout (b,s,n)
// ---------------------------------------------------------------------------
__global__ __launch_bounds__(256) void ue_pre(
    const float* __restrict__ x, const float* __restrict__ Ue_w,
    const float* __restrict__ Ue_b, float* __restrict__ ue)
{
    const int b = blockIdx.y;
    const int s0 = blockIdx.x * 32;
    const int n = threadIdx.x;
    __shared__ float xs[32][256];
    __shared__ float uws[32][32];

    float acc[32];
#pragma unroll
    for (int i = 0; i < 32; i++) acc[i] = 0.f;

#pragma unroll 1
    for (int tc = 0; tc < 4; tc++) {
        __syncthreads();
#pragma unroll
        for (int tt = 0; tt < 32; tt++)
            xs[tt][n] = x[(size_t)(tc * 32 + tt) * (B_ * N_) + b * N_ + n];
#pragma unroll
        for (int q = 0; q < 4; q++) {
            int e = q * 256 + n;
            int s = e >> 5, tt = e & 31;
            uws[s][tt] = Ue_w[(s0 + s) * T_ + tc * 32 + tt];
        }
        __syncthreads();
        float xr[32];
#pragma unroll
        for (int tt = 0; tt < 32; tt++) xr[tt] = xs[tt][n];
#pragma unroll
        for (int s = 0; s < 32; s++) {
            float a = acc[s];
#pragma unroll
            for (int tt = 0; tt < 32; tt++) a += xr[tt] * uws[s][tt];
            acc[s] = a;
        }
    }
#pragma unroll
    for (int s = 0; s < 32; s++)
        ue[((size_t)b * T_ + s0 + s) * N_ + n] = acc[s] + Ue_b[s0 + s];
}

// ---------------------------------------------------------------------------
// Persistent scan, 512 threads/block (8 waves/CU), group-local communication.
// Group g = blocks [g*32,+32) owns batches [g*64,+64).
// Part A (block sg): batches bA=g*64+sg*2, bB=bA+1.
//   we-GEMM: thread=(s,qr): K split 4-way, one We_p stream for both batches.
//   attention: thread=(half,sgrp,n4): float4 ue loads, 32 s-iters, LDS reduce.
// Part C: 64b x 64gc gates tile; waves 0-3 stage A, waves 4-7 stage W;
//   2x4 micro-tile; fused LSTM cell epilogue.
// ---------------------------------------------------------------------------
__global__ __launch_bounds__(512, 1) void scan_persist(
    const float* __restrict__ x, const float* __restrict__ h0,
    const float* __restrict__ We_p, const float* __restrict__ We_b,
    const float* __restrict__ ve_w, const float* __restrict__ ue,
    const float* __restrict__ Wg, const float* __restrict__ bg,
    float* __restrict__ cbuf, float* __restrict__ hseq,
    float* __restrict__ xtil, int* bar)
{
    const int tid = threadIdx.x;
    const int blk = blockIdx.x;
    const int g = blk >> 5;          // group 0..7
    const int sg = blk & 31;         // slot in group 0..31
    int* gbar = bar + g * 32;

    __shared__ __align__(16) float hcA[1024];
    __shared__ __align__(16) float hcB[1024];
    __shared__ float wepartA[512];
    __shared__ float wepartB[512];
    __shared__ float weA[128];
    __shared__ float weB[128];
    __shared__ float ve_s[128];
    __shared__ __align__(16) float ep[8][256];
    __shared__ float red[512];
    __shared__ __align__(16) float As[16][68];
    __shared__ __align__(16) float Ws[16][68];

    if (tid < 128) ve_s[tid] = ve_w[tid];

    // part A ids
    const int bA = g * 64 + sg * 2;
    const int bB = bA + 1;
    const int s_ = tid & 127;         // we-GEMM s
    const int qr = tid >> 7;          // we-GEMM K-quarter 0..3
    const int half = tid >> 8;        // attention batch half
    const int tt = tid & 255;
    const int sgrp = tt >> 6;         // attention s-quarter
    const int n4 = tt & 63;           // attention n/4
    // part C ids
    const int row0 = g * 64, col0 = sg * 64;
    const int tx = tid & 15, ty = tid >> 4;   // ty 0..31 (2 rows each)
    const int lh = tid >> 8;          // staging role: 0 = A-tile, 1 = W-tile
    const int lt = tid & 255;
    const int li = lt >> 2;           // staged row 0..63
    const int lk4 = (lt & 3) * 4;     // staged k offset

#pragma unroll 1
    for (int t = 0; t < T_; t++) {
        const float* hprev = t ? (hseq + (size_t)(t - 1) * (B_ * M_)) : h0;

        // ---------------- Part A: we + attention for bA,bB ----------------
        {
            hcA[tid]       = ld_dev(hprev + bA * M_ + tid);
            hcA[512 + tid] = ld_dev(cbuf + bA * M_ + tid);
            hcB[tid]       = ld_dev(hprev + bB * M_ + tid);
            hcB[512 + tid] = ld_dev(cbuf + bB * M_ + tid);
            __syncthreads();

            // we partials: 4-way K split, shared We_p stream
            float accA = 0.f, accB = 0.f;
            const float4* wp4 = (const float4*)We_p;
#pragma unroll 4
            for (int q = qr * 64; q < qr * 64 + 64; q++) {
                float4 w = wp4[q * 128 + s_];
                float4 a = *(const float4*)&hcA[q * 4];
                float4 b2 = *(const float4*)&hcB[q * 4];
                accA += w.x * a.x + w.y * a.y + w.z * a.z + w.w * a.w;
                accB += w.x * b2.x + w.y * b2.y + w.z * b2.z + w.w * b2.w;
            }
            wepartA[qr * 128 + s_] = accA;
            wepartB[qr * 128 + s_] = accB;
            __syncthreads();
            if (tid < 128) {
                float wb = We_b[tid];
                weA[tid] = wepartA[tid] + wepartA[128 + tid]
                         + wepartA[256 + tid] + wepartA[384 + tid] + wb;
                weB[tid] = wepartB[tid] + wepartB[128 + tid]
                         + wepartB[256 + tid] + wepartB[384 + tid] + wb;
            }
            __syncthreads();

            // attention: float4 ue loads, s-quarter per thread
            const int b = half ? bB : bA;
            const float* wes = half ? weB : weA;
            const float* up = ue + (size_t)b * (T_ * N_) + n4 * 4;
            float4 e4 = make_float4(0.f, 0.f, 0.f, 0.f);
#pragma unroll 4
            for (int ss = sgrp * 32; ss < sgrp * 32 + 32; ss++) {
                float4 u = *(const float4*)&up[(size_t)ss * N_];
                float w = wes[ss], v = ve_s[ss];
                e4.x += fast_tanh(w + u.x) * v;
                e4.y += fast_tanh(w + u.y) * v;
                e4.z += fast_tanh(w + u.z) * v;
                e4.w += fast_tanh(w + u.w) * v;
            }
            *(float4*)&ep[half * 4 + sgrp][n4 * 4] = e4;
            __syncthreads();
            float e = ep[half * 4 + 0][tt] + ep[half * 4 + 1][tt]
                    + ep[half * 4 + 2][tt] + ep[half * 4 + 3][tt];

            // softmax over n (256) within each half
            red[tid] = e; __syncthreads();
            for (int off = 128; off > 0; off >>= 1) {
                if (tt < off)
                    red[half * 256 + tt] = fmaxf(red[half * 256 + tt],
                                                 red[half * 256 + tt + off]);
                __syncthreads();
            }
            float mx = red[half * 256]; __syncthreads();
            float ex = __expf(e - mx);
            red[tid] = ex; __syncthreads();
            for (int off = 128; off > 0; off >>= 1) {
                if (tt < off)
                    red[half * 256 + tt] += red[half * 256 + tt + off];
                __syncthreads();
            }
            float alpha = __fdividef(ex, red[half * 256]);
            st_dev(&xtil[b * N_ + tt],
                   alpha * x[(size_t)t * (B_ * N_) + b * N_ + tt]);
        }
        group_bar(gbar, (t * 2 + 1) * GSZ);

        // -------- Part C: gates GEMM (64x64 tile) + fused cell --------
        {
            float acc[2][4];
#pragma unroll
            for (int r = 0; r < 2; r++)
#pragma unroll
                for (int cc = 0; cc < 4; cc++) acc[r][cc] = 0.f;

#pragma unroll 1
            for (int pass = 0; pass < 2; pass++) {
                const float* A = pass ? hprev : xtil;
                const int lda = pass ? M_ : N_;
                const int K = pass ? 512 : 256;
                const float* W = Wg + (pass ? 256 : 0);
                const float* arow = A + (size_t)(row0 + li) * lda + lk4;
                const float* wrow = W + (size_t)(col0 + li) * 768 + lk4;
                float a0 = 0.f, a1 = 0.f, a2 = 0.f, a3 = 0.f;
                float4 wv = make_float4(0.f, 0.f, 0.f, 0.f);
                if (lh == 0) {
                    a0 = ld_dev(arow + 0); a1 = ld_dev(arow + 1);
                    a2 = ld_dev(arow + 2); a3 = ld_dev(arow + 3);
                } else {
                    wv = *(const float4*)wrow;
                }
#pragma unroll 1
                for (int kk = 0; kk < K; kk += 16) {
                    __syncthreads();
                    if (lh == 0) {
                        As[lk4 + 0][li] = a0; As[lk4 + 1][li] = a1;
                        As[lk4 + 2][li] = a2; As[lk4 + 3][li] = a3;
                    } else {
                        Ws[lk4 + 0][li] = wv.x; Ws[lk4 + 1][li] = wv.y;
                        Ws[lk4 + 2][li] = wv.z; Ws[lk4 + 3][li] = wv.w;
                    }
                    __syncthreads();
                    if (kk + 16 < K) {
                        if (lh == 0) {
                            a0 = ld_dev(arow + kk + 16);
                            a1 = ld_dev(arow + kk + 17);
                            a2 = ld_dev(arow + kk + 18);
                            a3 = ld_dev(arow + kk + 19);
                        } else {
                            wv = *(const float4*)(wrow + kk + 16);
                        }
                    }
#pragma unroll
                    for (int k = 0; k < 16; k++) {
                        float2 a = *(const float2*)&As[k][ty * 2];
                        float4 w = *(const float4*)&Ws[k][tx * 4];
                        acc[0][0] += a.x * w.x; acc[0][1] += a.x * w.y;
                        acc[0][2] += a.x * w.z; acc[0][3] += a.x * w.w;
                        acc[1][0] += a.y * w.x; acc[1][1] += a.y * w.y;
                        acc[1][2] += a.y * w.z; acc[1][3] += a.y * w.w;
                    }
                }
            }

            // fused LSTM cell: m = col0/4 + tx, rows row0 + ty*2 + r
            const int m = (col0 >> 2) + tx;
            const float bi  = bg[col0 + tx * 4 + 0];
            const float bf  = bg[col0 + tx * 4 + 1];
            const float bgg = bg[col0 + tx * 4 + 2];
            const float bo  = bg[col0 + tx * 4 + 3];
            float* hseq_t = hseq + (size_t)t * (B_ * M_);
#pragma unroll
            for (int r = 0; r < 2; r++) {
                const int b = row0 + ty * 2 + r;
                const int idx = b * M_ + m;
                float gi = acc[r][0] + bi;
                float gf = acc[r][1] + bf;
                float gc = acc[r][2] + bgg;
                float go = acc[r][3] + bo;
                float cn = fast_sig(gf) * ld_dev(&cbuf[idx])
                         + fast_sig(gi) * fast_tanh(gc);
                st_dev(&cbuf[idx], cn);
                st_dev(&hseq_t[idx], fast_sig(go) * fast_tanh(cn));
            }
        }
        group_bar(gbar, (t * 2 + 2) * GSZ);
    }
}

// ---------------------------------------------------------------------------
// Post: l[b,t] += sum_m tanh(h_seq@Ud_w^T + Ud_b)*vd_w   (rows=T*B, cols=M)
// ---------------------------------------------------------------------------
__global__ __launch_bounds__(256) void gemm_l(
    const float* __restrict__ A1,
    const float* __restrict__ W1,
    const float* __restrict__ bias1,
    const float* __restrict__ vw, float* __restrict__ lout)
{
    __shared__ float As[16][68];
    __shared__ float Ws[16][68];
    __shared__ float rsum[64];

    const int tid = threadIdx.x;
    const int tx = tid & 15, ty = tid >> 4;
    const int row0 = blockIdx.y * 64;
    const int col0 = blockIdx.x * 64;
    const int li = tid >> 2;
    const int lk4 = (tid & 3) * 4;

    float acc[4][4];
#pragma unroll
    for (int r = 0; r < 4; r++)
#pragma unroll
        for (int cc = 0; cc < 4; cc++) acc[r][cc] = 0.f;

    float4 av = *(const float4*)&A1[(size_t)(row0 + li) * M_ + lk4];
    float4 wv = *(const float4*)&W1[(size_t)(col0 + li) * M_ + lk4];
#pragma unroll 1
    for (int kk = 0; kk < 512; kk += 16) {
        __syncthreads();
        As[lk4 + 0][li] = av.x; As[lk4 + 1][li] = av.y;
        As[lk4 + 2][li] = av.z; As[lk4 + 3][li] = av.w;
        Ws[lk4 + 0][li] = wv.x; Ws[lk4 + 1][li] = wv.y;
        Ws[lk4 + 2][li] = wv.z; Ws[lk4 + 3][li] = wv.w;
        __syncthreads();
        if (kk + 16 < 512) {
            av = *(const float4*)&A1[(size_t)(row0 + li) * M_ + kk + 16 + lk4];
            wv = *(const float4*)&W1[(size_t)(col0 + li) * M_ + kk + 16 + lk4];
        }
#pragma unroll
        for (int k = 0; k < 16; k++) {
            float4 a = *(const float4*)&As[k][ty * 4];
            float4 w = *(const float4*)&Ws[k][tx * 4];
            acc[0][0] += a.x * w.x; acc[0][1] += a.x * w.y;
            acc[0][2] += a.x * w.z; acc[0][3] += a.x * w.w;
            acc[1][0] += a.y * w.x; acc[1][1] += a.y * w.y;
            acc[1][2] += a.y * w.z; acc[1][3] += a.y * w.w;
            acc[2][0] += a.z * w.x; acc[2][1] += a.z * w.y;
            acc[2][2] += a.z * w.z; acc[2][3] += a.z * w.w;
            acc[3][0] += a.w * w.x; acc[3][1] += a.w * w.y;
            acc[3][2] += a.w * w.z; acc[3][3] += a.w * w.w;
        }
    }

    __syncthreads();
    if (tid < 64) rsum[tid] = 0.f;
    __syncthreads();
    float part[4] = {0.f, 0.f, 0.f, 0.f};
#pragma unroll
    for (int r = 0; r < 4; r++)
#pragma unroll
        for (int cc = 0; cc < 4; cc++) {
            int gc = col0 + tx * 4 + cc;
            part[r] += fast_tanh(acc[r][cc] + bias1[gc]) * vw[gc];
        }
#pragma unroll
    for (int r = 0; r < 4; r++)
        atomicAdd(&rsum[ty * 4 + r], part[r]);
    __syncthreads();
    if (tid < 64) {
        int gr = row0 + tid;          // gr = t*512 + b
        int b = gr & 511, t = gr >> 9;
        atomicAdd(&lout[b * 128 + t], rsum[tid]);
    }
}

// ---------------------------------------------------------------------------
// Final: beta = softmax_t(l); ctx = sum_t beta*h_seq; logits = ctx.out_w+out_b
// ---------------------------------------------------------------------------
__global__ __launch_bounds__(512) void final_kernel(
    const float* __restrict__ lbuf, const float* __restrict__ hseq,
    const float* __restrict__ out_w, const float* __restrict__ out_b,
    float* __restrict__ out)
{
    const int b = blockIdx.x;
    const int tid = threadIdx.x;
    __shared__ float beta_s[128];
    __shared__ float red[512];

    float lv = (tid < 128) ? lbuf[b * 128 + tid] : -1e30f;
    red[tid] = lv; __syncthreads();
    for (int off = 256; off >= 1; off >>= 1) {
        if (tid < off) red[tid] = fmaxf(red[tid], red[tid + off]);
        __syncthreads();
    }
    float mx = red[0]; __syncthreads();
    float ex = (tid < 128) ? __expf(lv - mx) : 0.f;
    red[tid] = ex; __syncthreads();
    for (int off = 256; off >= 1; off >>= 1) {
        if (tid < off) red[tid] += red[tid + off];
        __syncthreads();
    }
    float denom = red[0];
    if (tid < 128) {
        float bt = ex / denom;
        beta_s[tid] = bt;
        out[512 + b * 128 + tid] = bt;
    }
    __syncthreads();

    float ctx = 0.f;
#pragma unroll 4
    for (int t = 0; t < 128; t++)
        ctx += beta_s[t] * hseq[(size_t)t * (B_ * M_) + b * M_ + tid];

    red[tid] = ctx * out_w[tid]; __syncthreads();
    for (int off = 256; off >= 1; off >>= 1) {
        if (tid < off) red[tid] += red[tid + off];
        __syncthreads();
    }
    if (tid == 0) out[b] = red[0] + out_b[0];
}

// ---------------------------------------------------------------------------
extern "C" void kernel_launch(void* const* d_in, const int* in_sizes, int n_in,
                              void* d_out, int out_size, void* d_ws, size_t ws_size,
                              hipStream_t stream)
{
    const float* x    = (const float*)d_in[0];
    const float* h0   = (const float*)d_in[1];
    const float* c0   = (const float*)d_in[2];
    const float* Wih  = (const float*)d_in[3];
    const float* Whh  = (const float*)d_in[4];
    const float* b_ih = (const float*)d_in[5];
    const float* b_hh = (const float*)d_in[6];
    const float* We_w = (const float*)d_in[7];
    const float* We_b = (const float*)d_in[8];
    const float* Ue_w = (const float*)d_in[9];
    const float* Ue_b = (const float*)d_in[10];
    const float* ve_w = (const float*)d_in[11];
    const float* Ud_w = (const float*)d_in[13];
    const float* Ud_b = (const float*)d_in[14];
    const float* vd_w = (const float*)d_in[15];
    const float* out_w = (const float*)d_in[17];
    const float* out_b = (const float*)d_in[18];
    float* out = (float*)d_out;

    // workspace layout (floats). lbuf aliases xt (disjoint lifetimes).
    float* ws    = (float*)d_ws;
    float* ue    = ws;                       // 16,777,216  (B*T*N)
    float* hseq  = ue + 16777216;            // 33,554,432  (T*B*M)
    float* cbuf  = hseq + 33554432;          //    262,144  (B*M)
    float* xt    = cbuf + 262144;            //    131,072  (B*N)  [scan only]
    float* lbuf  = xt;                       //     65,536  (B*T)  [post only]
    float* Wg    = xt + 131072;              //  1,572,864  (2048*768)
    float* bgv   = Wg + 1572864;             //      2,048
    float* We_p  = bgv + 2048;               //    131,072  (256*128*4)
    int*   bar   = (int*)(We_p + 131072);    //   8*32 ints

    hipMemcpyAsync(cbuf, c0, (size_t)B_ * M_ * 4, hipMemcpyDeviceToDevice, stream);
    hipMemsetAsync(bar, 0, 8 * 32 * 4, stream);

    prep_wg<<<2048, 256, 0, stream>>>(Wih, Whh, b_ih, b_hh, Wg, bgv);
    prep_wep<<<512, 256, 0, stream>>>(We_w, We_p);
    ue_pre<<<dim3(4, 512), 256, 0, stream>>>(x, Ue_w, Ue_b, ue);

    scan_persist<<<NBLK, 512, 0, stream>>>(
        x, h0, We_p, We_b, ve_w, ue, Wg, bgv, cbuf, hseq, xt, bar);

    hipMemsetAsync(lbuf, 0, (size_t)B_ * T_ * 4, stream);
    gemm_l<<<dim3(8, 1024), 256, 0, stream>>>(hseq, Ud_w, Ud_b, vd_w, lbuf);
    final_kernel<<<512, 512, 0, stream>>>(lbuf, hseq, out_w, out_b, out);
}

// Round 7
// 6334.475 us; speedup vs baseline: 3.9910x; 1.5098x over previous
//
#include <hip/hip_runtime.h>
#include <math.h>

// Problem dims
#define T_ 128
#define B_ 512
#define N_ 256
#define M_ 512
#define G_ 2048   // 4*M
#define NBLK 256  // 8 groups x 32 blocks, 1 block/CU, 512 threads = 8 waves/CU
#define GSZ 32    // blocks per group
#define KC_ 24    // K chunks of 32 (768 total: 256 x-tilde + 512 h)

typedef unsigned long long ull;
typedef __attribute__((ext_vector_type(8))) short short8v;
typedef __attribute__((ext_vector_type(4))) float float4v;

// ---------------------------------------------------------------------------
// Device-coherent access, relaxed (sc1): no cache flush, cross-XCD safe
// ---------------------------------------------------------------------------
__device__ __forceinline__ float ld_dev(const float* p) {
    return __hip_atomic_load(const_cast<float*>(p), __ATOMIC_RELAXED,
                             __HIP_MEMORY_SCOPE_AGENT);
}
__device__ __forceinline__ void st_dev(float* p, float v) {
    __hip_atomic_store(p, v, __ATOMIC_RELAXED, __HIP_MEMORY_SCOPE_AGENT);
}
__device__ __forceinline__ ull ld_dev64(const ull* p) {
    return __hip_atomic_load(const_cast<ull*>(p), __ATOMIC_RELAXED,
                             __HIP_MEMORY_SCOPE_AGENT);
}
__device__ __forceinline__ void st_dev64(ull* p, ull v) {
    __hip_atomic_store(p, v, __ATOMIC_RELAXED, __HIP_MEMORY_SCOPE_AGENT);
}

// Fast transcendentals (abs err ~1e-6, threshold 1e-3)
__device__ __forceinline__ float fast_tanh(float x) {
    float e = __expf(2.f * x);
    return 1.f - __fdividef(2.f, e + 1.f);
}
__device__ __forceinline__ float fast_sig(float x) {
    return __fdividef(1.f, 1.f + __expf(-x));
}

// bf16 helpers (RNE)
__device__ __forceinline__ unsigned short bf16_rne(float f) {
    unsigned u = __float_as_uint(f);
    return (unsigned short)((u + 0x7FFFu + ((u >> 16) & 1u)) >> 16);
}
__device__ __forceinline__ float bf16_tof(unsigned short h) {
    return __uint_as_float(((unsigned)h) << 16);
}
__device__ __forceinline__ ull pack4(const unsigned short* s) {
    return (ull)s[0] | ((ull)s[1] << 16) | ((ull)s[2] << 32) | ((ull)s[3] << 48);
}

// ---------------------------------------------------------------------------
// Group barrier: 32 blocks, relaxed ticket, no L2 flush.
// ---------------------------------------------------------------------------
__device__ __forceinline__ void group_bar(int* gbar, int goal) {
    __syncthreads();
    if (threadIdx.x == 0) {
        asm volatile("s_waitcnt vmcnt(0)" ::: "memory");
        __hip_atomic_fetch_add(gbar, 1, __ATOMIC_RELAXED,
                               __HIP_MEMORY_SCOPE_AGENT);
        while (__hip_atomic_load(gbar, __ATOMIC_RELAXED,
                                 __HIP_MEMORY_SCOPE_AGENT) < goal) {
            __builtin_amdgcn_s_sleep(1);
        }
    }
    __syncthreads();
}

// ---------------------------------------------------------------------------
// Prep: fused bias bg[4m+g] = b_ih[g*512+m] + b_hh[g*512+m]
// ---------------------------------------------------------------------------
__global__ __launch_bounds__(256) void prep_bg(
    const float* __restrict__ bih, const float* __restrict__ bhh,
    float* __restrict__ bg)
{
    int rp = blockIdx.x * 256 + threadIdx.x;
    if (rp < 2048) {
        int m = rp >> 2, g = rp & 3;
        int row = g * 512 + m;
        bg[rp] = bih[row] + bhh[row];
    }
}

// ---------------------------------------------------------------------------
// Prep: Wt fragment-tiled bf16 hi/lo planes.
// Unit uid = (ct*24 + kc)*64 + lane; col = ct*16 + (lane&15) (gate-interleaved
// 4m+g), k = kc*32 + (lane>>4)*8 + j.  16B per unit per plane.
// ---------------------------------------------------------------------------
__global__ __launch_bounds__(256) void prep_wt(
    const float* __restrict__ Wih, const float* __restrict__ Whh,
    uint4* __restrict__ Wt_hi, uint4* __restrict__ Wt_lo)
{
    int uid = blockIdx.x * 256 + threadIdx.x;   // < 196608
    int ct = uid / (KC_ * 64);
    int rem = uid % (KC_ * 64);
    int kc = rem >> 6, lane = rem & 63;
    int col = ct * 16 + (lane & 15);
    int m = col >> 2, gi = col & 3;
    int grow = gi * 512 + m;
    int quad = lane >> 4;
    union { unsigned short s[8]; uint4 v; } hi, lo;
#pragma unroll
    for (int j = 0; j < 8; j++) {
        int k = kc * 32 + quad * 8 + j;
        float v = (k < 256) ? Wih[(size_t)grow * 256 + k]
                            : Whh[(size_t)grow * 512 + (k - 256)];
        hi.s[j] = bf16_rne(v);
        lo.s[j] = bf16_rne(v - bf16_tof(hi.s[j]));
    }
    Wt_hi[uid] = hi.v;
    Wt_lo[uid] = lo.v;
}

// We_p[q][s][j] = We_w[s][q*4+j]
__global__ __launch_bounds__(256) void prep_wep(
    const float* __restrict__ We_w, float* __restrict__ We_p)
{
    int idx = blockIdx.x * 256 + threadIdx.x;   // < 131072
    int q = idx >> 9, rest = idx & 511, s = rest >> 2, j = rest & 3;
    We_p[idx] = We_w[s * 1024 + q * 4 + j];
}

// ---------------------------------------------------------------------------
// Precompute Ue_x[b,s,n] layout (b,s,n)
// ---------------------------------------------------------------------------
__global__ __launch_bounds__(256) void ue_pre(
    const float* __restrict__ x, const float* __restrict__ Ue_w,
    const float* __restrict__ Ue_b, float* __restrict__ ue)
{
    const int b = blockIdx.y;
    const int s0 = blockIdx.x * 32;
    const int n = threadIdx.x;
    __shared__ float xs[32][256];
    __shared__ float uws[32][32];

    float acc[32];
#pragma unroll
    for (int i = 0; i < 32; i++) acc[i] = 0.f;

#pragma unroll 1
    for (int tc = 0; tc < 4; tc++) {
        __syncthreads();
#pragma unroll
        for (int tt = 0; tt < 32; tt++)
            xs[tt][n] = x[(size_t)(tc * 32 + tt) * (B_ * N_) + b * N_ + n];
#pragma unroll
        for (int q = 0; q < 4; q++) {
            int e = q * 256 + n;
            int s = e >> 5, tt = e & 31;
            uws[s][tt] = Ue_w[(s0 + s) * T_ + tc * 32 + tt];
        }
        __syncthreads();
        float xr[32];
#pragma unroll
        for (int tt = 0; tt < 32; tt++) xr[tt] = xs[tt][n];
#pragma unroll
        for (int s = 0; s < 32; s++) {
            float a = acc[s];
#pragma unroll
            for (int tt = 0; tt < 32; tt++) a += xr[tt] * uws[s][tt];
            acc[s] = a;
        }
    }
#pragma unroll
    for (int s = 0; s < 32; s++)
        ue[((size_t)b * T_ + s0 + s) * N_ + n] = acc[s] + Ue_b[s0 + s];
}

// ---------------------------------------------------------------------------
// Persistent scan. 512 thr/block, group-local comm.
// Part A (block sg): batches bA=g*64+sg*2, bB=bA+1: we-GEMM + attention;
//   then emits x_tilde(t) AND h(t-1) into fragment-tiled bf16 hi/lo planes
//   At[(rt*24+kc)*64+lane][8] (rt=row/16, k=kc*32+quad*8+j, lane=quad*16+row15).
// Part C: 64x64 gates tile per block via MFMA 16x16x32 bf16 split-precision:
//   D = aH*wH + aH*wL + aL*wH  (3 mfma). No LDS in K-loop; fragments loaded
//   straight from global (A: sc1 8B atomics; W: plain, L2-hot). Fused cell.
// ---------------------------------------------------------------------------
__global__ __launch_bounds__(512, 1) void scan_persist(
    const float* __restrict__ x, const float* __restrict__ h0,
    const float* __restrict__ We_p, const float* __restrict__ We_b,
    const float* __restrict__ ve_w, const float* __restrict__ ue,
    const short8v* __restrict__ Wt_hi, const short8v* __restrict__ Wt_lo,
    const float* __restrict__ bg,
    float* __restrict__ cbuf, float* __restrict__ hseq,
    ull* __restrict__ At_hi, ull* __restrict__ At_lo, int* bar)
{
    const int tid = threadIdx.x;
    const int blk = blockIdx.x;
    const int g = blk >> 5;          // group 0..7
    const int sg = blk & 31;         // slot in group
    int* gbar = bar + g * 32;

    __shared__ __align__(16) float hcA[1024];
    __shared__ __align__(16) float hcB[1024];
    __shared__ float wepartA[512];
    __shared__ float wepartB[512];
    __shared__ float weA[128];
    __shared__ float weB[128];
    __shared__ float ve_s[128];
    __shared__ __align__(16) float ep[8][256];
    __shared__ float red[512];
    __shared__ float xs[2][256];
    __shared__ float gates_s[64][65];

    if (tid < 128) ve_s[tid] = ve_w[tid];

    // part A ids
    const int bA = g * 64 + sg * 2;
    const int bB = bA + 1;
    const int s_ = tid & 127;
    const int qr = tid >> 7;
    const int half = tid >> 8;
    const int tt = tid & 255;
    const int sgrp = tt >> 6;
    const int n4 = tt & 63;
    // part C ids
    const int lane = tid & 63;
    const int w = tid >> 6;          // wave 0..7
    const int rtC = g * 4 + (w & 3);
    const int ctA = sg * 4 + (w >> 2) * 2;
    const int ctB = ctA + 1;
    const int quad = lane >> 4;

#pragma unroll 1
    for (int t = 0; t < T_; t++) {
        const float* hprev = t ? (hseq + (size_t)(t - 1) * (B_ * M_)) : h0;

        // ---------------- Part A ----------------
        {
            hcA[tid]       = ld_dev(hprev + bA * M_ + tid);
            hcA[512 + tid] = ld_dev(cbuf + bA * M_ + tid);
            hcB[tid]       = ld_dev(hprev + bB * M_ + tid);
            hcB[512 + tid] = ld_dev(cbuf + bB * M_ + tid);
            __syncthreads();

            // we partials: 4-way K split, shared We_p stream
            float accA = 0.f, accB = 0.f;
            const float4* wp4 = (const float4*)We_p;
#pragma unroll 4
            for (int q = qr * 64; q < qr * 64 + 64; q++) {
                float4 wv = wp4[q * 128 + s_];
                float4 a = *(const float4*)&hcA[q * 4];
                float4 b2 = *(const float4*)&hcB[q * 4];
                accA += wv.x * a.x + wv.y * a.y + wv.z * a.z + wv.w * a.w;
                accB += wv.x * b2.x + wv.y * b2.y + wv.z * b2.z + wv.w * b2.w;
            }
            wepartA[qr * 128 + s_] = accA;
            wepartB[qr * 128 + s_] = accB;
            __syncthreads();
            if (tid < 128) {
                float wb = We_b[tid];
                weA[tid] = wepartA[tid] + wepartA[128 + tid]
                         + wepartA[256 + tid] + wepartA[384 + tid] + wb;
                weB[tid] = wepartB[tid] + wepartB[128 + tid]
                         + wepartB[256 + tid] + wepartB[384 + tid] + wb;
            }
            __syncthreads();

            // attention: float4 ue loads, s-quarter per thread
            const int b = half ? bB : bA;
            const float* wes = half ? weB : weA;
            const float* up = ue + (size_t)b * (T_ * N_) + n4 * 4;
            float4 e4 = make_float4(0.f, 0.f, 0.f, 0.f);
#pragma unroll 4
            for (int ss = sgrp * 32; ss < sgrp * 32 + 32; ss++) {
                float4 u = *(const float4*)&up[(size_t)ss * N_];
                float wv = wes[ss], v = ve_s[ss];
                e4.x += fast_tanh(wv + u.x) * v;
                e4.y += fast_tanh(wv + u.y) * v;
                e4.z += fast_tanh(wv + u.z) * v;
                e4.w += fast_tanh(wv + u.w) * v;
            }
            *(float4*)&ep[half * 4 + sgrp][n4 * 4] = e4;
            __syncthreads();
            float e = ep[half * 4 + 0][tt] + ep[half * 4 + 1][tt]
                    + ep[half * 4 + 2][tt] + ep[half * 4 + 3][tt];

            red[tid] = e; __syncthreads();
            for (int off = 128; off > 0; off >>= 1) {
                if (tt < off)
                    red[half * 256 + tt] = fmaxf(red[half * 256 + tt],
                                                 red[half * 256 + tt + off]);
                __syncthreads();
            }
            float mx = red[half * 256]; __syncthreads();
            float ex = __expf(e - mx);
            red[tid] = ex; __syncthreads();
            for (int off = 128; off > 0; off >>= 1) {
                if (tt < off)
                    red[half * 256 + tt] += red[half * 256 + tt + off];
                __syncthreads();
            }
            float alpha = __fdividef(ex, red[half * 256]);
            xs[half][tt] = alpha * x[(size_t)t * (B_ * N_) + b * N_ + tt];
            __syncthreads();

            // ---- emit tiled bf16 hi/lo: h(t-1) (128 units) + x~(t) (64) ----
            if (tid < 192) {
                int rowsel, kc, qd;
                float v[8];
                if (tid < 128) {                 // h region, kc 8..23
                    rowsel = tid >> 6;
                    int q2 = tid & 63;
                    kc = 8 + (q2 >> 2); qd = q2 & 3;
                    const float* hcX = rowsel ? hcB : hcA;
                    int mb = (kc - 8) * 32 + qd * 8;
#pragma unroll
                    for (int j = 0; j < 8; j++) v[j] = hcX[mb + j];
                } else {                         // x~ region, kc 0..7
                    int u2 = tid - 128;
                    rowsel = u2 >> 5;
                    int q2 = u2 & 31;
                    kc = q2 >> 2; qd = q2 & 3;
                    int nb = kc * 32 + qd * 8;
#pragma unroll
                    for (int j = 0; j < 8; j++) v[j] = xs[rowsel][nb + j];
                }
                int b2 = bA + rowsel;
                int rt = b2 >> 4;
                int ln = qd * 16 + (b2 & 15);
                size_t uidx = ((size_t)(rt * KC_ + kc) * 64 + ln) * 2; // ull idx
                unsigned short hi[8], lo[8];
#pragma unroll
                for (int j = 0; j < 8; j++) {
                    hi[j] = bf16_rne(v[j]);
                    lo[j] = bf16_rne(v[j] - bf16_tof(hi[j]));
                }
                st_dev64(At_hi + uidx,     pack4(hi));
                st_dev64(At_hi + uidx + 1, pack4(hi + 4));
                st_dev64(At_lo + uidx,     pack4(lo));
                st_dev64(At_lo + uidx + 1, pack4(lo + 4));
            }
        }
        group_bar(gbar, (t * 2 + 1) * GSZ);

        // -------- Part C: MFMA gates GEMM + fused cell --------
        {
            float4v acc0 = {0.f, 0.f, 0.f, 0.f};
            float4v acc1 = {0.f, 0.f, 0.f, 0.f};

            size_t aidx = ((size_t)(rtC * KC_ + 0) * 64 + lane) * 2;
            ull pah0 = ld_dev64(At_hi + aidx), pah1 = ld_dev64(At_hi + aidx + 1);
            ull pal0 = ld_dev64(At_lo + aidx), pal1 = ld_dev64(At_lo + aidx + 1);
            short8v pw0h = Wt_hi[(ctA * KC_ + 0) * 64 + lane];
            short8v pw0l = Wt_lo[(ctA * KC_ + 0) * 64 + lane];
            short8v pw1h = Wt_hi[(ctB * KC_ + 0) * 64 + lane];
            short8v pw1l = Wt_lo[(ctB * KC_ + 0) * 64 + lane];

#pragma unroll 1
            for (int kc = 0; kc < KC_; kc++) {
                ull ah0 = pah0, ah1 = pah1, al0 = pal0, al1 = pal1;
                short8v w0h = pw0h, w0l = pw0l, w1h = pw1h, w1l = pw1l;
                if (kc + 1 < KC_) {
                    size_t ai = ((size_t)(rtC * KC_ + kc + 1) * 64 + lane) * 2;
                    pah0 = ld_dev64(At_hi + ai); pah1 = ld_dev64(At_hi + ai + 1);
                    pal0 = ld_dev64(At_lo + ai); pal1 = ld_dev64(At_lo + ai + 1);
                    pw0h = Wt_hi[(ctA * KC_ + kc + 1) * 64 + lane];
                    pw0l = Wt_lo[(ctA * KC_ + kc + 1) * 64 + lane];
                    pw1h = Wt_hi[(ctB * KC_ + kc + 1) * 64 + lane];
                    pw1l = Wt_lo[(ctB * KC_ + kc + 1) * 64 + lane];
                }
                union { ull u[2]; short8v s; } aH, aL;
                aH.u[0] = ah0; aH.u[1] = ah1;
                aL.u[0] = al0; aL.u[1] = al1;
                acc0 = __builtin_amdgcn_mfma_f32_16x16x32_bf16(aH.s, w0h, acc0, 0, 0, 0);
                acc1 = __builtin_amdgcn_mfma_f32_16x16x32_bf16(aH.s, w1h, acc1, 0, 0, 0);
                acc0 = __builtin_amdgcn_mfma_f32_16x16x32_bf16(aH.s, w0l, acc0, 0, 0, 0);
                acc1 = __builtin_amdgcn_mfma_f32_16x16x32_bf16(aH.s, w1l, acc1, 0, 0, 0);
                acc0 = __builtin_amdgcn_mfma_f32_16x16x32_bf16(aL.s, w0h, acc0, 0, 0, 0);
                acc1 = __builtin_amdgcn_mfma_f32_16x16x32_bf16(aL.s, w1h, acc1, 0, 0, 0);
            }

            // dump C/D (col=lane&15, row=quad*4+reg) into gates tile
            const int r0 = (w & 3) * 16;
            const int c0l = (w >> 2) * 32;
#pragma unroll
            for (int r = 0; r < 4; r++) {
                gates_s[r0 + quad * 4 + r][c0l + (lane & 15)] = acc0[r];
                gates_s[r0 + quad * 4 + r][c0l + 16 + (lane & 15)] = acc1[r];
            }
            __syncthreads();

            // fused cell: 1024 cells (64 b x 16 m), 2 per thread
            float* hseq_t = hseq + (size_t)t * (B_ * M_);
#pragma unroll
            for (int pass = 0; pass < 2; pass++) {
                int cid = tid + pass * 512;
                int b_l = cid >> 4, mi = cid & 15;
                float gi = gates_s[b_l][mi * 4 + 0] + bg[sg * 64 + mi * 4 + 0];
                float gf = gates_s[b_l][mi * 4 + 1] + bg[sg * 64 + mi * 4 + 1];
                float gc = gates_s[b_l][mi * 4 + 2] + bg[sg * 64 + mi * 4 + 2];
                float go = gates_s[b_l][mi * 4 + 3] + bg[sg * 64 + mi * 4 + 3];
                int idx = (g * 64 + b_l) * M_ + sg * 16 + mi;
                float cn = fast_sig(gf) * ld_dev(&cbuf[idx])
                         + fast_sig(gi) * fast_tanh(gc);
                st_dev(&cbuf[idx], cn);
                st_dev(&hseq_t[idx], fast_sig(go) * fast_tanh(cn));
            }
        }
        group_bar(gbar, (t * 2 + 2) * GSZ);
    }
}

// ---------------------------------------------------------------------------
// Post: l[b,t] += sum_m tanh(h_seq@Ud_w^T + Ud_b)*vd_w   (rows=T*B, cols=M)
// ---------------------------------------------------------------------------
__global__ __launch_bounds__(256) void gemm_l(
    const float* __restrict__ A1,
    const float* __restrict__ W1,
    const float* __restrict__ bias1,
    const float* __restrict__ vw, float* __restrict__ lout)
{
    __shared__ float As[16][68];
    __shared__ float Ws[16][68];
    __shared__ float rsum[64];

    const int tid = threadIdx.x;
    const int tx = tid & 15, ty = tid >> 4;
    const int row0 = blockIdx.y * 64;
    const int col0 = blockIdx.x * 64;
    const int li = tid >> 2;
    const int lk4 = (tid & 3) * 4;

    float acc[4][4];
#pragma unroll
    for (int r = 0; r < 4; r++)
#pragma unroll
        for (int cc = 0; cc < 4; cc++) acc[r][cc] = 0.f;

    float4 av = *(const float4*)&A1[(size_t)(row0 + li) * M_ + lk4];
    float4 wv = *(const float4*)&W1[(size_t)(col0 + li) * M_ + lk4];
#pragma unroll 1
    for (int kk = 0; kk < 512; kk += 16) {
        __syncthreads();
        As[lk4 + 0][li] = av.x; As[lk4 + 1][li] = av.y;
        As[lk4 + 2][li] = av.z; As[lk4 + 3][li] = av.w;
        Ws[lk4 + 0][li] = wv.x; Ws[lk4 + 1][li] = wv.y;
        Ws[lk4 + 2][li] = wv.z; Ws[lk4 + 3][li] = wv.w;
        __syncthreads();
        if (kk + 16 < 512) {
            av = *(const float4*)&A1[(size_t)(row0 + li) * M_ + kk + 16 + lk4];
            wv = *(const float4*)&W1[(size_t)(col0 + li) * M_ + kk + 16 + lk4];
        }
#pragma unroll
        for (int k = 0; k < 16; k++) {
            float4 a = *(const float4*)&As[k][ty * 4];
            float4 w2 = *(const float4*)&Ws[k][tx * 4];
            acc[0][0] += a.x * w2.x; acc[0][1] += a.x * w2.y;
            acc[0][2] += a.x * w2.z; acc[0][3] += a.x * w2.w;
            acc[1][0] += a.y * w2.x; acc[1][1] += a.y * w2.y;
            acc[1][2] += a.y * w2.z; acc[1][3] += a.y * w2.w;
            acc[2][0] += a.z * w2.x; acc[2][1] += a.z * w2.y;
            acc[2][2] += a.z * w2.z; acc[2][3] += a.z * w2.w;
            acc[3][0] += a.w * w2.x; acc[3][1] += a.w * w2.y;
            acc[3][2] += a.w * w2.z; acc[3][3] += a.w * w2.w;
        }
    }

    __syncthreads();
    if (tid < 64) rsum[tid] = 0.f;
    __syncthreads();
    float part[4] = {0.f, 0.f, 0.f, 0.f};
#pragma unroll
    for (int r = 0; r < 4; r++)
#pragma unroll
        for (int cc = 0; cc < 4; cc++) {
            int gc = col0 + tx * 4 + cc;
            part[r] += fast_tanh(acc[r][cc] + bias1[gc]) * vw[gc];
        }
#pragma unroll
    for (int r = 0; r < 4; r++)
        atomicAdd(&rsum[ty * 4 + r], part[r]);
    __syncthreads();
    if (tid < 64) {
        int gr = row0 + tid;          // gr = t*512 + b
        int b = gr & 511, t = gr >> 9;
        atomicAdd(&lout[b * 128 + t], rsum[tid]);
    }
}

// ---------------------------------------------------------------------------
// Final: beta = softmax_t(l); ctx = sum_t beta*h_seq; logits = ctx.out_w+out_b
// ---------------------------------------------------------------------------
__global__ __launch_bounds__(512) void final_kernel(
    const float* __restrict__ lbuf, const float* __restrict__ hseq,
    const float* __restrict__ out_w, const float* __restrict__ out_b,
    float* __restrict__ out)
{
    const int b = blockIdx.x;
    const int tid = threadIdx.x;
    __shared__ float beta_s[128];
    __shared__ float red[512];

    float lv = (tid < 128) ? lbuf[b * 128 + tid] : -1e30f;
    red[tid] = lv; __syncthreads();
    for (int off = 256; off >= 1; off >>= 1) {
        if (tid < off) red[tid] = fmaxf(red[tid], red[tid + off]);
        __syncthreads();
    }
    float mx = red[0]; __syncthreads();
    float ex = (tid < 128) ? __expf(lv - mx) : 0.f;
    red[tid] = ex; __syncthreads();
    for (int off = 256; off >= 1; off >>= 1) {
        if (tid < off) red[tid] += red[tid + off];
        __syncthreads();
    }
    float denom = red[0];
    if (tid < 128) {
        float bt = ex / denom;
        beta_s[tid] = bt;
        out[512 + b * 128 + tid] = bt;
    }
    __syncthreads();

    float ctx = 0.f;
#pragma unroll 4
    for (int t = 0; t < 128; t++)
        ctx += beta_s[t] * hseq[(size_t)t * (B_ * M_) + b * M_ + tid];

    red[tid] = ctx * out_w[tid]; __syncthreads();
    for (int off = 256; off >= 1; off >>= 1) {
        if (tid < off) red[tid] += red[tid + off];
        __syncthreads();
    }
    if (tid == 0) out[b] = red[0] + out_b[0];
}

// ---------------------------------------------------------------------------
extern "C" void kernel_launch(void* const* d_in, const int* in_sizes, int n_in,
                              void* d_out, int out_size, void* d_ws, size_t ws_size,
                              hipStream_t stream)
{
    const float* x    = (const float*)d_in[0];
    const float* h0   = (const float*)d_in[1];
    const float* c0   = (const float*)d_in[2];
    const float* Wih  = (const float*)d_in[3];
    const float* Whh  = (const float*)d_in[4];
    const float* b_ih = (const float*)d_in[5];
    const float* b_hh = (const float*)d_in[6];
    const float* We_w = (const float*)d_in[7];
    const float* We_b = (const float*)d_in[8];
    const float* Ue_w = (const float*)d_in[9];
    const float* Ue_b = (const float*)d_in[10];
    const float* ve_w = (const float*)d_in[11];
    const float* Ud_w = (const float*)d_in[13];
    const float* Ud_b = (const float*)d_in[14];
    const float* vd_w = (const float*)d_in[15];
    const float* out_w = (const float*)d_in[17];
    const float* out_b = (const float*)d_in[18];
    float* out = (float*)d_out;

    // workspace layout (float slots). lbuf aliases ue (disjoint lifetimes).
    float* ws    = (float*)d_ws;
    float* ue    = ws;                       // 16,777,216  (B*T*N) [scan only]
    float* lbuf  = ws;                       //     65,536  (B*T)   [post only]
    float* hseq  = ue + 16777216;            // 33,554,432  (T*B*M)
    float* cbuf  = hseq + 33554432;          //    262,144  (B*M)
    float* We_p  = cbuf + 262144;            //    131,072
    float* bgv   = We_p + 131072;            //      2,048
    float* At_hi = bgv + 2048;               //    196,608  (32*24*64*8 bf16)
    float* At_lo = At_hi + 196608;           //    196,608
    float* Wt_hi = At_lo + 196608;           //    786,432  (128*24*64*8 bf16)
    float* Wt_lo = Wt_hi + 786432;           //    786,432
    int*   bar   = (int*)(Wt_lo + 786432);   //   8*32 ints

    hipMemcpyAsync(cbuf, c0, (size_t)B_ * M_ * 4, hipMemcpyDeviceToDevice, stream);
    hipMemsetAsync(bar, 0, 8 * 32 * 4, stream);

    prep_bg<<<8, 256, 0, stream>>>(b_ih, b_hh, bgv);
    prep_wt<<<768, 256, 0, stream>>>(Wih, Whh, (uint4*)Wt_hi, (uint4*)Wt_lo);
    prep_wep<<<512, 256, 0, stream>>>(We_w, We_p);
    ue_pre<<<dim3(4, 512), 256, 0, stream>>>(x, Ue_w, Ue_b, ue);

    scan_persist<<<NBLK, 512, 0, stream>>>(
        x, h0, We_p, We_b, ve_w, ue,
        (const short8v*)Wt_hi, (const short8v*)Wt_lo, bgv,
        cbuf, hseq, (ull*)At_hi, (ull*)At_lo, bar);

    hipMemsetAsync(lbuf, 0, (size_t)B_ * T_ * 4, stream);
    gemm_l<<<dim3(8, 1024), 256, 0, stream>>>(hseq, Ud_w, Ud_b, vd_w, lbuf);
    final_kernel<<<512, 512, 0, stream>>>(lbuf, hseq, out_w, out_b, out);
}

// Round 8
// 5588.649 us; speedup vs baseline: 4.5237x; 1.1335x over previous
//
#include <hip/hip_runtime.h>
#include <math.h>

// Problem dims
#define T_ 128
#define B_ 512
#define N_ 256
#define M_ 512
#define G_ 2048   // 4*M
#define NBLK 256  // 8 groups x 32 blocks, 1 block/CU, 512 threads = 8 waves/CU
#define GSZ 32    // blocks per group
#define KC_ 24    // K chunks of 32 (768 total: 256 x-tilde + 512 h)

typedef unsigned long long ull;
typedef __attribute__((ext_vector_type(8))) short short8v;
typedef __attribute__((ext_vector_type(4))) float float4v;

// ---------------------------------------------------------------------------
// Device-coherent access, relaxed (sc1): no cache flush, cross-XCD safe
// ---------------------------------------------------------------------------
__device__ __forceinline__ float ld_dev(const float* p) {
    return __hip_atomic_load(const_cast<float*>(p), __ATOMIC_RELAXED,
                             __HIP_MEMORY_SCOPE_AGENT);
}
__device__ __forceinline__ void st_dev(float* p, float v) {
    __hip_atomic_store(p, v, __ATOMIC_RELAXED, __HIP_MEMORY_SCOPE_AGENT);
}
__device__ __forceinline__ ull ld_dev64(const ull* p) {
    return __hip_atomic_load(const_cast<ull*>(p), __ATOMIC_RELAXED,
                             __HIP_MEMORY_SCOPE_AGENT);
}
__device__ __forceinline__ void st_dev64(ull* p, ull v) {
    __hip_atomic_store(p, v, __ATOMIC_RELAXED, __HIP_MEMORY_SCOPE_AGENT);
}

// Fast transcendentals (abs err ~1e-6, threshold 1e-3)
__device__ __forceinline__ float fast_tanh(float x) {
    float e = __expf(2.f * x);
    return 1.f - __fdividef(2.f, e + 1.f);
}
__device__ __forceinline__ float fast_sig(float x) {
    return __fdividef(1.f, 1.f + __expf(-x));
}

// bf16 helpers (RNE)
__device__ __forceinline__ unsigned short bf16_rne(float f) {
    unsigned u = __float_as_uint(f);
    return (unsigned short)((u + 0x7FFFu + ((u >> 16) & 1u)) >> 16);
}
__device__ __forceinline__ float bf16_tof(unsigned short h) {
    return __uint_as_float(((unsigned)h) << 16);
}
__device__ __forceinline__ ull pack4(const unsigned short* s) {
    return (ull)s[0] | ((ull)s[1] << 16) | ((ull)s[2] << 32) | ((ull)s[3] << 48);
}

// ---------------------------------------------------------------------------
// Group barrier: 32 blocks, relaxed ticket, no L2 flush.
// ---------------------------------------------------------------------------
__device__ __forceinline__ void group_bar(int* gbar, int goal) {
    __syncthreads();
    if (threadIdx.x == 0) {
        asm volatile("s_waitcnt vmcnt(0)" ::: "memory");
        __hip_atomic_fetch_add(gbar, 1, __ATOMIC_RELAXED,
                               __HIP_MEMORY_SCOPE_AGENT);
        while (__hip_atomic_load(gbar, __ATOMIC_RELAXED,
                                 __HIP_MEMORY_SCOPE_AGENT) < goal) {
            __builtin_amdgcn_s_sleep(1);
        }
    }
    __syncthreads();
}

// ---------------------------------------------------------------------------
// Prep: fused bias bg[4m+g] = b_ih[g*512+m] + b_hh[g*512+m]
// ---------------------------------------------------------------------------
__global__ __launch_bounds__(256) void prep_bg(
    const float* __restrict__ bih, const float* __restrict__ bhh,
    float* __restrict__ bg)
{
    int rp = blockIdx.x * 256 + threadIdx.x;
    if (rp < 2048) {
        int m = rp >> 2, g = rp & 3;
        int row = g * 512 + m;
        bg[rp] = bih[row] + bhh[row];
    }
}

// ---------------------------------------------------------------------------
// Prep: Wt fragment-tiled bf16 hi/lo planes.
// ---------------------------------------------------------------------------
__global__ __launch_bounds__(256) void prep_wt(
    const float* __restrict__ Wih, const float* __restrict__ Whh,
    uint4* __restrict__ Wt_hi, uint4* __restrict__ Wt_lo)
{
    int uid = blockIdx.x * 256 + threadIdx.x;   // < 196608
    int ct = uid / (KC_ * 64);
    int rem = uid % (KC_ * 64);
    int kc = rem >> 6, lane = rem & 63;
    int col = ct * 16 + (lane & 15);
    int m = col >> 2, gi = col & 3;
    int grow = gi * 512 + m;
    int quad = lane >> 4;
    union { unsigned short s[8]; uint4 v; } hi, lo;
#pragma unroll
    for (int j = 0; j < 8; j++) {
        int k = kc * 32 + quad * 8 + j;
        float v = (k < 256) ? Wih[(size_t)grow * 256 + k]
                            : Whh[(size_t)grow * 512 + (k - 256)];
        hi.s[j] = bf16_rne(v);
        lo.s[j] = bf16_rne(v - bf16_tof(hi.s[j]));
    }
    Wt_hi[uid] = hi.v;
    Wt_lo[uid] = lo.v;
}

// We_p[q][s][j] = We_w[s][q*4+j]
__global__ __launch_bounds__(256) void prep_wep(
    const float* __restrict__ We_w, float* __restrict__ We_p)
{
    int idx = blockIdx.x * 256 + threadIdx.x;   // < 131072
    int q = idx >> 9, rest = idx & 511, s = rest >> 2, j = rest & 3;
    We_p[idx] = We_w[s * 1024 + q * 4 + j];
}

// ---------------------------------------------------------------------------
// Precompute Ue_x + Ue_b, packed bf16 s-pairs:
// ue_pk[(b*64 + s/2)*256 + n] = bf16(ue[b][s][n]) | bf16(ue[b][s+1][n])<<16
// ---------------------------------------------------------------------------
__global__ __launch_bounds__(256) void ue_pre(
    const float* __restrict__ x, const float* __restrict__ Ue_w,
    const float* __restrict__ Ue_b, unsigned* __restrict__ ue_pk)
{
    const int b = blockIdx.y;
    const int s0 = blockIdx.x * 32;
    const int n = threadIdx.x;
    __shared__ float xs[32][256];
    __shared__ float uws[32][32];

    float acc[32];
#pragma unroll
    for (int i = 0; i < 32; i++) acc[i] = 0.f;

#pragma unroll 1
    for (int tc = 0; tc < 4; tc++) {
        __syncthreads();
#pragma unroll
        for (int tt = 0; tt < 32; tt++)
            xs[tt][n] = x[(size_t)(tc * 32 + tt) * (B_ * N_) + b * N_ + n];
#pragma unroll
        for (int q = 0; q < 4; q++) {
            int e = q * 256 + n;
            int s = e >> 5, tt = e & 31;
            uws[s][tt] = Ue_w[(s0 + s) * T_ + tc * 32 + tt];
        }
        __syncthreads();
        float xr[32];
#pragma unroll
        for (int tt = 0; tt < 32; tt++) xr[tt] = xs[tt][n];
#pragma unroll
        for (int s = 0; s < 32; s++) {
            float a = acc[s];
#pragma unroll
            for (int tt = 0; tt < 32; tt++) a += xr[tt] * uws[s][tt];
            acc[s] = a;
        }
    }
#pragma unroll
    for (int i = 0; i < 16; i++) {
        float v0 = acc[2 * i] + Ue_b[s0 + 2 * i];
        float v1 = acc[2 * i + 1] + Ue_b[s0 + 2 * i + 1];
        unsigned pk = (unsigned)bf16_rne(v0) | ((unsigned)bf16_rne(v1) << 16);
        ue_pk[((size_t)b * 64 + (s0 >> 1) + i) * 256 + n] = pk;
    }
}

// ---------------------------------------------------------------------------
// Persistent scan. 512 thr/block. ue held in 64 VGPRs/thread for all 128
// steps (thread (blk,half,tt) <-> (batch, n): exactly B*N threads chip-wide).
// Part A: we-GEMM + register-resident attention + At emit (bf16 hi/lo tiled).
// Part C: MFMA 16x16x32 bf16 split-precision gates GEMM + fused LSTM cell.
// ---------------------------------------------------------------------------
__global__ __launch_bounds__(512, 1) void scan_persist(
    const float* __restrict__ x, const float* __restrict__ h0,
    const float* __restrict__ We_p, const float* __restrict__ We_b,
    const float* __restrict__ ve_w, const unsigned* __restrict__ ue_pk,
    const short8v* __restrict__ Wt_hi, const short8v* __restrict__ Wt_lo,
    const float* __restrict__ bg,
    float* __restrict__ cbuf, float* __restrict__ hseq,
    ull* __restrict__ At_hi, ull* __restrict__ At_lo, int* bar)
{
    const int tid = threadIdx.x;
    const int blk = blockIdx.x;
    const int g = blk >> 5;          // group 0..7
    const int sg = blk & 31;         // slot in group
    int* gbar = bar + g * 32;

    __shared__ __align__(16) float hcA[1024];
    __shared__ __align__(16) float hcB[1024];
    __shared__ float wepartA[512];
    __shared__ float wepartB[512];
    __shared__ __align__(16) float wv[2][256];   // [half][s*2+{we,ve}]
    __shared__ float ve_s[128];
    __shared__ float red[512];
    __shared__ float xs[2][256];
    __shared__ float gates_s[64][65];

    // part A ids
    const int bA = g * 64 + sg * 2;
    const int bB = bA + 1;
    const int s_ = tid & 127;
    const int qr = tid >> 7;
    const int half = tid >> 8;       // batch half (wave-uniform)
    const int tt = tid & 255;        // n
    // part C ids
    const int lane = tid & 63;
    const int w = tid >> 6;          // wave 0..7
    const int rtC = g * 4 + (w & 3);
    const int ctA = sg * 4 + (w >> 2) * 2;
    const int ctB = ctA + 1;
    const int quad = lane >> 4;

    if (tid < 128) {
        float v = ve_w[tid];
        ve_s[tid] = v;
        wv[0][tid * 2 + 1] = v;      // ve entries constant across t
        wv[1][tid * 2 + 1] = v;
    }

    // ---- one-time: load this thread's ue slice (all 128 s) into VGPRs ----
    unsigned ureg[64];
    {
        const unsigned* up = ue_pk + ((size_t)(bA + half) * 64) * 256 + tt;
#pragma unroll
        for (int i = 0; i < 64; i++) ureg[i] = up[(size_t)i * 256];
    }

#pragma unroll 1
    for (int t = 0; t < T_; t++) {
        const float* hprev = t ? (hseq + (size_t)(t - 1) * (B_ * M_)) : h0;

        // ---------------- Part A ----------------
        {
            hcA[tid]       = ld_dev(hprev + bA * M_ + tid);
            hcA[512 + tid] = ld_dev(cbuf + bA * M_ + tid);
            hcB[tid]       = ld_dev(hprev + bB * M_ + tid);
            hcB[512 + tid] = ld_dev(cbuf + bB * M_ + tid);
            __syncthreads();

            // we partials: 4-way K split, shared We_p stream
            float accA = 0.f, accB = 0.f;
            const float4* wp4 = (const float4*)We_p;
#pragma unroll 4
            for (int q = qr * 64; q < qr * 64 + 64; q++) {
                float4 wq = wp4[q * 128 + s_];
                float4 a = *(const float4*)&hcA[q * 4];
                float4 b2 = *(const float4*)&hcB[q * 4];
                accA += wq.x * a.x + wq.y * a.y + wq.z * a.z + wq.w * a.w;
                accB += wq.x * b2.x + wq.y * b2.y + wq.z * b2.z + wq.w * b2.w;
            }
            wepartA[qr * 128 + s_] = accA;
            wepartB[qr * 128 + s_] = accB;
            __syncthreads();
            if (tid < 128) {
                float wb = We_b[tid];
                wv[0][tid * 2] = wepartA[tid] + wepartA[128 + tid]
                               + wepartA[256 + tid] + wepartA[384 + tid] + wb;
                wv[1][tid * 2] = wepartB[tid] + wepartB[128 + tid]
                               + wepartB[256 + tid] + wepartB[384 + tid] + wb;
            }
            __syncthreads();

            // attention: ue from registers, we/ve via uniform b128 broadcast
            float e = 0.f;
#pragma unroll
            for (int i = 0; i < 64; i++) {
                unsigned u = ureg[i];
                float u0 = __uint_as_float(u << 16);
                float u1 = __uint_as_float(u & 0xFFFF0000u);
                float4 q = *(const float4*)&wv[half][i * 4];
                e += fast_tanh(q.x + u0) * q.y;
                e += fast_tanh(q.z + u1) * q.w;
            }

            // softmax over n (256) within each half
            red[tid] = e; __syncthreads();
            for (int off = 128; off > 0; off >>= 1) {
                if (tt < off)
                    red[half * 256 + tt] = fmaxf(red[half * 256 + tt],
                                                 red[half * 256 + tt + off]);
                __syncthreads();
            }
            float mx = red[half * 256]; __syncthreads();
            float ex = __expf(e - mx);
            red[tid] = ex; __syncthreads();
            for (int off = 128; off > 0; off >>= 1) {
                if (tt < off)
                    red[half * 256 + tt] += red[half * 256 + tt + off];
                __syncthreads();
            }
            float alpha = __fdividef(ex, red[half * 256]);
            xs[half][tt] = alpha * x[(size_t)t * (B_ * N_) + (bA + half) * N_ + tt];
            __syncthreads();

            // ---- emit tiled bf16 hi/lo: h(t-1) (128 units) + x~(t) (64) ----
            if (tid < 192) {
                int rowsel, kc, qd;
                float v[8];
                if (tid < 128) {                 // h region, kc 8..23
                    rowsel = tid >> 6;
                    int q2 = tid & 63;
                    kc = 8 + (q2 >> 2); qd = q2 & 3;
                    const float* hcX = rowsel ? hcB : hcA;
                    int mb = (kc - 8) * 32 + qd * 8;
#pragma unroll
                    for (int j = 0; j < 8; j++) v[j] = hcX[mb + j];
                } else {                         // x~ region, kc 0..7
                    int u2 = tid - 128;
                    rowsel = u2 >> 5;
                    int q2 = u2 & 31;
                    kc = q2 >> 2; qd = q2 & 3;
                    int nb = kc * 32 + qd * 8;
#pragma unroll
                    for (int j = 0; j < 8; j++) v[j] = xs[rowsel][nb + j];
                }
                int b2 = bA + rowsel;
                int rt = b2 >> 4;
                int ln = qd * 16 + (b2 & 15);
                size_t uidx = ((size_t)(rt * KC_ + kc) * 64 + ln) * 2; // ull idx
                unsigned short hi[8], lo[8];
#pragma unroll
                for (int j = 0; j < 8; j++) {
                    hi[j] = bf16_rne(v[j]);
                    lo[j] = bf16_rne(v[j] - bf16_tof(hi[j]));
                }
                st_dev64(At_hi + uidx,     pack4(hi));
                st_dev64(At_hi + uidx + 1, pack4(hi + 4));
                st_dev64(At_lo + uidx,     pack4(lo));
                st_dev64(At_lo + uidx + 1, pack4(lo + 4));
            }
        }
        group_bar(gbar, (t * 2 + 1) * GSZ);

        // -------- Part C: MFMA gates GEMM + fused cell --------
        {
            float4v acc0 = {0.f, 0.f, 0.f, 0.f};
            float4v acc1 = {0.f, 0.f, 0.f, 0.f};

            size_t aidx = ((size_t)(rtC * KC_ + 0) * 64 + lane) * 2;
            ull pah0 = ld_dev64(At_hi + aidx), pah1 = ld_dev64(At_hi + aidx + 1);
            ull pal0 = ld_dev64(At_lo + aidx), pal1 = ld_dev64(At_lo + aidx + 1);
            short8v pw0h = Wt_hi[(ctA * KC_ + 0) * 64 + lane];
            short8v pw0l = Wt_lo[(ctA * KC_ + 0) * 64 + lane];
            short8v pw1h = Wt_hi[(ctB * KC_ + 0) * 64 + lane];
            short8v pw1l = Wt_lo[(ctB * KC_ + 0) * 64 + lane];

#pragma unroll 1
            for (int kc = 0; kc < KC_; kc++) {
                ull ah0 = pah0, ah1 = pah1, al0 = pal0, al1 = pal1;
                short8v w0h = pw0h, w0l = pw0l, w1h = pw1h, w1l = pw1l;
                if (kc + 1 < KC_) {
                    size_t ai = ((size_t)(rtC * KC_ + kc + 1) * 64 + lane) * 2;
                    pah0 = ld_dev64(At_hi + ai); pah1 = ld_dev64(At_hi + ai + 1);
                    pal0 = ld_dev64(At_lo + ai); pal1 = ld_dev64(At_lo + ai + 1);
                    pw0h = Wt_hi[(ctA * KC_ + kc + 1) * 64 + lane];
                    pw0l = Wt_lo[(ctA * KC_ + kc + 1) * 64 + lane];
                    pw1h = Wt_hi[(ctB * KC_ + kc + 1) * 64 + lane];
                    pw1l = Wt_lo[(ctB * KC_ + kc + 1) * 64 + lane];
                }
                union { ull u[2]; short8v s; } aH, aL;
                aH.u[0] = ah0; aH.u[1] = ah1;
                aL.u[0] = al0; aL.u[1] = al1;
                acc0 = __builtin_amdgcn_mfma_f32_16x16x32_bf16(aH.s, w0h, acc0, 0, 0, 0);
                acc1 = __builtin_amdgcn_mfma_f32_16x16x32_bf16(aH.s, w1h, acc1, 0, 0, 0);
                acc0 = __builtin_amdgcn_mfma_f32_16x16x32_bf16(aH.s, w0l, acc0, 0, 0, 0);
                acc1 = __builtin_amdgcn_mfma_f32_16x16x32_bf16(aH.s, w1l, acc1, 0, 0, 0);
                acc0 = __builtin_amdgcn_mfma_f32_16x16x32_bf16(aL.s, w0h, acc0, 0, 0, 0);
                acc1 = __builtin_amdgcn_mfma_f32_16x16x32_bf16(aL.s, w1h, acc1, 0, 0, 0);
            }

            // dump C/D (col=lane&15, row=quad*4+reg) into gates tile
            const int r0 = (w & 3) * 16;
            const int c0l = (w >> 2) * 32;
#pragma unroll
            for (int r = 0; r < 4; r++) {
                gates_s[r0 + quad * 4 + r][c0l + (lane & 15)] = acc0[r];
                gates_s[r0 + quad * 4 + r][c0l + 16 + (lane & 15)] = acc1[r];
            }
            __syncthreads();

            // fused cell: 1024 cells (64 b x 16 m), 2 per thread
            float* hseq_t = hseq + (size_t)t * (B_ * M_);
#pragma unroll
            for (int pass = 0; pass < 2; pass++) {
                int cid = tid + pass * 512;
                int b_l = cid >> 4, mi = cid & 15;
                float gi = gates_s[b_l][mi * 4 + 0] + bg[sg * 64 + mi * 4 + 0];
                float gf = gates_s[b_l][mi * 4 + 1] + bg[sg * 64 + mi * 4 + 1];
                float gc = gates_s[b_l][mi * 4 + 2] + bg[sg * 64 + mi * 4 + 2];
                float go = gates_s[b_l][mi * 4 + 3] + bg[sg * 64 + mi * 4 + 3];
                int idx = (g * 64 + b_l) * M_ + sg * 16 + mi;
                float cn = fast_sig(gf) * ld_dev(&cbuf[idx])
                         + fast_sig(gi) * fast_tanh(gc);
                st_dev(&cbuf[idx], cn);
                st_dev(&hseq_t[idx], fast_sig(go) * fast_tanh(cn));
            }
        }
        group_bar(gbar, (t * 2 + 2) * GSZ);
    }
}

// ---------------------------------------------------------------------------
// Post: l[b,t] += sum_m tanh(h_seq@Ud_w^T + Ud_b)*vd_w   (rows=T*B, cols=M)
// ---------------------------------------------------------------------------
__global__ __launch_bounds__(256) void gemm_l(
    const float* __restrict__ A1,
    const float* __restrict__ W1,
    const float* __restrict__ bias1,
    const float* __restrict__ vw, float* __restrict__ lout)
{
    __shared__ float As[16][68];
    __shared__ float Ws[16][68];
    __shared__ float rsum[64];

    const int tid = threadIdx.x;
    const int tx = tid & 15, ty = tid >> 4;
    const int row0 = blockIdx.y * 64;
    const int col0 = blockIdx.x * 64;
    const int li = tid >> 2;
    const int lk4 = (tid & 3) * 4;

    float acc[4][4];
#pragma unroll
    for (int r = 0; r < 4; r++)
#pragma unroll
        for (int cc = 0; cc < 4; cc++) acc[r][cc] = 0.f;

    float4 av = *(const float4*)&A1[(size_t)(row0 + li) * M_ + lk4];
    float4 wvv = *(const float4*)&W1[(size_t)(col0 + li) * M_ + lk4];
#pragma unroll 1
    for (int kk = 0; kk < 512; kk += 16) {
        __syncthreads();
        As[lk4 + 0][li] = av.x; As[lk4 + 1][li] = av.y;
        As[lk4 + 2][li] = av.z; As[lk4 + 3][li] = av.w;
        Ws[lk4 + 0][li] = wvv.x; Ws[lk4 + 1][li] = wvv.y;
        Ws[lk4 + 2][li] = wvv.z; Ws[lk4 + 3][li] = wvv.w;
        __syncthreads();
        if (kk + 16 < 512) {
            av = *(const float4*)&A1[(size_t)(row0 + li) * M_ + kk + 16 + lk4];
            wvv = *(const float4*)&W1[(size_t)(col0 + li) * M_ + kk + 16 + lk4];
        }
#pragma unroll
        for (int k = 0; k < 16; k++) {
            float4 a = *(const float4*)&As[k][ty * 4];
            float4 w2 = *(const float4*)&Ws[k][tx * 4];
            acc[0][0] += a.x * w2.x; acc[0][1] += a.x * w2.y;
            acc[0][2] += a.x * w2.z; acc[0][3] += a.x * w2.w;
            acc[1][0] += a.y * w2.x; acc[1][1] += a.y * w2.y;
            acc[1][2] += a.y * w2.z; acc[1][3] += a.y * w2.w;
            acc[2][0] += a.z * w2.x; acc[2][1] += a.z * w2.y;
            acc[2][2] += a.z * w2.z; acc[2][3] += a.z * w2.w;
            acc[3][0] += a.w * w2.x; acc[3][1] += a.w * w2.y;
            acc[3][2] += a.w * w2.z; acc[3][3] += a.w * w2.w;
        }
    }

    __syncthreads();
    if (tid < 64) rsum[tid] = 0.f;
    __syncthreads();
    float part[4] = {0.f, 0.f, 0.f, 0.f};
#pragma unroll
    for (int r = 0; r < 4; r++)
#pragma unroll
        for (int cc = 0; cc < 4; cc++) {
            int gc = col0 + tx * 4 + cc;
            part[r] += fast_tanh(acc[r][cc] + bias1[gc]) * vw[gc];
        }
#pragma unroll
    for (int r = 0; r < 4; r++)
        atomicAdd(&rsum[ty * 4 + r], part[r]);
    __syncthreads();
    if (tid < 64) {
        int gr = row0 + tid;          // gr = t*512 + b
        int b = gr & 511, t = gr >> 9;
        atomicAdd(&lout[b * 128 + t], rsum[tid]);
    }
}

// ---------------------------------------------------------------------------
// Final: beta = softmax_t(l); ctx = sum_t beta*h_seq; logits = ctx.out_w+out_b
// ---------------------------------------------------------------------------
__global__ __launch_bounds__(512) void final_kernel(
    const float* __restrict__ lbuf, const float* __restrict__ hseq,
    const float* __restrict__ out_w, const float* __restrict__ out_b,
    float* __restrict__ out)
{
    const int b = blockIdx.x;
    const int tid = threadIdx.x;
    __shared__ float beta_s[128];
    __shared__ float red[512];

    float lv = (tid < 128) ? lbuf[b * 128 + tid] : -1e30f;
    red[tid] = lv; __syncthreads();
    for (int off = 256; off >= 1; off >>= 1) {
        if (tid < off) red[tid] = fmaxf(red[tid], red[tid + off]);
        __syncthreads();
    }
    float mx = red[0]; __syncthreads();
    float ex = (tid < 128) ? __expf(lv - mx) : 0.f;
    red[tid] = ex; __syncthreads();
    for (int off = 256; off >= 1; off >>= 1) {
        if (tid < off) red[tid] += red[tid + off];
        __syncthreads();
    }
    float denom = red[0];
    if (tid < 128) {
        float bt = ex / denom;
        beta_s[tid] = bt;
        out[512 + b * 128 + tid] = bt;
    }
    __syncthreads();

    float ctx = 0.f;
#pragma unroll 4
    for (int t = 0; t < 128; t++)
        ctx += beta_s[t] * hseq[(size_t)t * (B_ * M_) + b * M_ + tid];

    red[tid] = ctx * out_w[tid]; __syncthreads();
    for (int off = 256; off >= 1; off >>= 1) {
        if (tid < off) red[tid] += red[tid + off];
        __syncthreads();
    }
    if (tid == 0) out[b] = red[0] + out_b[0];
}

// ---------------------------------------------------------------------------
extern "C" void kernel_launch(void* const* d_in, const int* in_sizes, int n_in,
                              void* d_out, int out_size, void* d_ws, size_t ws_size,
                              hipStream_t stream)
{
    const float* x    = (const float*)d_in[0];
    const float* h0   = (const float*)d_in[1];
    const float* c0   = (const float*)d_in[2];
    const float* Wih  = (const float*)d_in[3];
    const float* Whh  = (const float*)d_in[4];
    const float* b_ih = (const float*)d_in[5];
    const float* b_hh = (const float*)d_in[6];
    const float* We_w = (const float*)d_in[7];
    const float* We_b = (const float*)d_in[8];
    const float* Ue_w = (const float*)d_in[9];
    const float* Ue_b = (const float*)d_in[10];
    const float* ve_w = (const float*)d_in[11];
    const float* Ud_w = (const float*)d_in[13];
    const float* Ud_b = (const float*)d_in[14];
    const float* vd_w = (const float*)d_in[15];
    const float* out_w = (const float*)d_in[17];
    const float* out_b = (const float*)d_in[18];
    float* out = (float*)d_out;

    // workspace layout (float slots). lbuf aliases ue_pk (disjoint lifetimes).
    float* ws    = (float*)d_ws;
    float* ue_pk = ws;                       //  8,388,608  (B*64*N uints) [scan]
    float* lbuf  = ws;                       //     65,536  (B*T)   [post only]
    float* hseq  = ue_pk + 8388608;          // 33,554,432  (T*B*M)
    float* cbuf  = hseq + 33554432;          //    262,144  (B*M)
    float* We_p  = cbuf + 262144;            //    131,072
    float* bgv   = We_p + 131072;            //      2,048
    float* At_hi = bgv + 2048;               //    196,608  (32*24*64*8 bf16)
    float* At_lo = At_hi + 196608;           //    196,608
    float* Wt_hi = At_lo + 196608;           //    786,432  (128*24*64*8 bf16)
    float* Wt_lo = Wt_hi + 786432;           //    786,432
    int*   bar   = (int*)(Wt_lo + 786432);   //   8*32 ints

    hipMemcpyAsync(cbuf, c0, (size_t)B_ * M_ * 4, hipMemcpyDeviceToDevice, stream);
    hipMemsetAsync(bar, 0, 8 * 32 * 4, stream);

    prep_bg<<<8, 256, 0, stream>>>(b_ih, b_hh, bgv);
    prep_wt<<<768, 256, 0, stream>>>(Wih, Whh, (uint4*)Wt_hi, (uint4*)Wt_lo);
    prep_wep<<<512, 256, 0, stream>>>(We_w, We_p);
    ue_pre<<<dim3(4, 512), 256, 0, stream>>>(x, Ue_w, Ue_b, (unsigned*)ue_pk);

    scan_persist<<<NBLK, 512, 0, stream>>>(
        x, h0, We_p, We_b, ve_w, (const unsigned*)ue_pk,
        (const short8v*)Wt_hi, (const short8v*)Wt_lo, bgv,
        cbuf, hseq, (ull*)At_hi, (ull*)At_lo, bar);

    hipMemsetAsync(lbuf, 0, (size_t)B_ * T_ * 4, stream);
    gemm_l<<<dim3(8, 1024), 256, 0, stream>>>(hseq, Ud_w, Ud_b, vd_w, lbuf);
    final_kernel<<<512, 512, 0, stream>>>(lbuf, hseq, out_w, out_b, out);
}